// Round 1
// baseline (7669.260 us; speedup 1.0000x reference)
//
#include <hip/hip_runtime.h>
#include <stdint.h>

#define N_NODESC 50000
#define N_EDGESC 200000
#define D_INC 128
#define DC 256
#define N_LAYERSC 4
#define N_RELC 4
#define NUM_MC 1024
#define NUM_RC 64

// ---------------- threefry2x32 (JAX-compatible) ----------------
__host__ __device__ __forceinline__ uint32_t rotl32(uint32_t x, int r){ return (x<<r)|(x>>(32-r)); }

__host__ __device__ inline void tf2x32(uint32_t k0, uint32_t k1, uint32_t x0, uint32_t x1,
                                       uint32_t* o0, uint32_t* o1){
  uint32_t k2 = k0 ^ k1 ^ 0x1BD11BDAu;
#define TFR(r) { x0 += x1; x1 = rotl32(x1, (r)); x1 ^= x0; }
  x0 += k0; x1 += k1;
  TFR(13) TFR(15) TFR(26) TFR(6)
  x0 += k1; x1 += k2 + 1u;
  TFR(17) TFR(29) TFR(16) TFR(24)
  x0 += k2; x1 += k0 + 2u;
  TFR(13) TFR(15) TFR(26) TFR(6)
  x0 += k0; x1 += k1 + 3u;
  TFR(17) TFR(29) TFR(16) TFR(24)
  x0 += k1; x1 += k2 + 4u;
  TFR(13) TFR(15) TFR(26) TFR(6)
  x0 += k2; x1 += k0 + 5u;
#undef TFR
  *o0 = x0; *o1 = x1;
}

// XLA f32 ErfInv (Giles polynomial)
__device__ __forceinline__ float erfinv_f32(float x){
  float w = -log1pf(-x*x);
  float p;
  if (w < 5.0f){
    w -= 2.5f;
    p = 2.81022636e-08f;
    p = fmaf(p, w, 3.43273939e-07f);
    p = fmaf(p, w, -3.5233877e-06f);
    p = fmaf(p, w, -4.39150654e-06f);
    p = fmaf(p, w, 0.00021858087f);
    p = fmaf(p, w, -0.00125372503f);
    p = fmaf(p, w, -0.00417768164f);
    p = fmaf(p, w, 0.246640727f);
    p = fmaf(p, w, 1.50140941f);
  } else {
    w = sqrtf(w) - 3.0f;
    p = -0.000200214257f;
    p = fmaf(p, w, 0.000100950558f);
    p = fmaf(p, w, 0.00134934322f);
    p = fmaf(p, w, -0.00367342844f);
    p = fmaf(p, w, 0.00573950773f);
    p = fmaf(p, w, -0.0076224613f);
    p = fmaf(p, w, 0.00943887047f);
    p = fmaf(p, w, 1.00167406f);
    p = fmaf(p, w, 2.83297682f);
  }
  return p*x;
}

__device__ __forceinline__ float bits_to_unit(uint32_t b){  // [0,1)
  return __uint_as_float((b >> 9) | 0x3f800000u) - 1.0f;
}

__device__ __forceinline__ float bits_to_normal(uint32_t b){
  float f = bits_to_unit(b);
  const float lo = -0.99999994f;           // nextafter(-1,0)
  float u = f * (1.0f - lo) + lo;          // scale folds to exactly 2.0f like JAX
  u = fmaxf(u, lo);
  return 1.41421356f * erfinv_f32(u);
}

__device__ __forceinline__ float waveReduce(float v){
  #pragma unroll
  for (int m = 1; m < 64; m <<= 1) v += __shfl_xor(v, m, 64);
  return v;
}

// ---------------- utility kernels ----------------
__global__ __launch_bounds__(256) void k_zero4(float4* p, int n4){
  int i = blockIdx.x*256 + threadIdx.x;
  if (i < n4) p[i] = make_float4(0.f,0.f,0.f,0.f);
}

__global__ __launch_bounds__(256) void k_count(const int* __restrict__ ei, const int* __restrict__ et,
                                               float* __restrict__ cnt, int* __restrict__ relmeta){
  int e = blockIdx.x*256 + threadIdx.x;
  if (e >= N_EDGESC) return;
  int r = et[e], dstv = ei[N_EDGESC + e];
  atomicAdd(&cnt[(size_t)r*N_NODESC + dstv], 1.0f);
  atomicAdd(&relmeta[r], 1);
}

__global__ void k_prefix(int* relmeta){
  relmeta[4] = 0;
  for (int r = 0; r < 4; r++) relmeta[5+r] = relmeta[4+r] + relmeta[r];
}

__global__ __launch_bounds__(256) void k_fill(const int* __restrict__ et, int* __restrict__ relmeta,
                                              int* __restrict__ rel_edges){
  int e = blockIdx.x*256 + threadIdx.x;
  if (e >= N_EDGESC) return;
  int r = et[e];
  int pos = atomicAdd(&relmeta[9+r], 1);
  rel_edges[relmeta[4+r] + pos] = e;
}

// one wave per edge of relation r: tmp[dst] += feats[src] / max(cnt,1)
__global__ __launch_bounds__(256) void k_scatter(const float* __restrict__ feats, float* __restrict__ tmp,
                                                 const int* __restrict__ rel_edges, const int* __restrict__ relmeta,
                                                 int r, const int* __restrict__ ei, const float* __restrict__ cnt){
  int wave = threadIdx.x >> 6, lane = threadIdx.x & 63;
  int widx = blockIdx.x*4 + wave;
  int base = relmeta[4+r];
  int cr   = relmeta[5+r] - base;
  if (widx >= cr) return;
  int e = rel_edges[base + widx];
  int src = ei[e], dst = ei[N_EDGESC + e];
  float invc = 1.0f / fmaxf(cnt[(size_t)r*N_NODESC + dst], 1.0f);
  const float4 v = *(const float4*)(feats + (size_t)src*DC + lane*4);
  float* tp = tmp + (size_t)dst*DC + lane*4;
  atomicAdd(tp+0, v.x*invc);
  atomicAdd(tp+1, v.y*invc);
  atomicAdd(tp+2, v.z*invc);
  atomicAdd(tp+3, v.w*invc);
}

// ---------------- generic fp32 GEMM: C(+)= A@B (+bias)(relu) -----------
// flags: 1=accumulate into C, 2=add bias, 4=relu
__global__ __launch_bounds__(256) void k_gemm(
    const float* __restrict__ A, int lda,
    const float* __restrict__ B, int ldb,
    float* __restrict__ C, int ldc,
    int M, int N, int K,
    const float* __restrict__ bias, int flags)
{
  __shared__ __align__(16) float As[64][36];
  __shared__ __align__(16) float Bs[32][64];
  const int tid = threadIdx.x;
  const int tx = tid & 15, ty = tid >> 4;
  const int m0 = blockIdx.y * 64, n0 = blockIdx.x * 64;
  const int am = tid >> 2, ak = (tid & 3) * 8;
  const int bk = tid >> 3, bn = (tid & 7) * 8;
  float acc[4][4] = {};
  for (int k0 = 0; k0 < K; k0 += 32){
    float4 a0, a1;
    int arow = m0 + am;
    if (arow < M){
      const float* ap = A + (size_t)arow*lda + (k0 + ak);
      a0 = *(const float4*)ap;
      a1 = *(const float4*)(ap + 4);
    } else {
      a0 = make_float4(0,0,0,0); a1 = a0;
    }
    const float* bp = B + (size_t)(k0 + bk)*ldb + (n0 + bn);
    float4 b0v = *(const float4*)bp;
    float4 b1v = *(const float4*)(bp + 4);
    *(float4*)&As[am][ak]   = a0;
    *(float4*)&As[am][ak+4] = a1;
    *(float4*)&Bs[bk][bn]   = b0v;
    *(float4*)&Bs[bk][bn+4] = b1v;
    __syncthreads();
    #pragma unroll
    for (int kk = 0; kk < 32; ++kk){
      float av[4], bv[4];
      #pragma unroll
      for (int i=0;i<4;i++) av[i] = As[ty*4+i][kk];
      #pragma unroll
      for (int j=0;j<4;j++) bv[j] = Bs[kk][tx*4+j];
      #pragma unroll
      for (int i=0;i<4;i++)
        #pragma unroll
        for (int j=0;j<4;j++)
          acc[i][j] = fmaf(av[i], bv[j], acc[i][j]);
    }
    __syncthreads();
  }
  #pragma unroll
  for (int i=0;i<4;i++){
    int row = m0 + ty*4 + i;
    if (row >= M) continue;
    #pragma unroll
    for (int j=0;j<4;j++){
      int col = n0 + tx*4 + j;
      float v = acc[i][j];
      if (flags & 2) v += bias[col];
      if (flags & 1) v += C[(size_t)row*ldc + col];
      if (flags & 4) v = fmaxf(v, 0.0f);
      C[(size_t)row*ldc + col] = v;
    }
  }
}

// ---------------- pooling & head kernels ----------------
__global__ __launch_bounds__(256) void k_gsum(const float* __restrict__ feats, const int* __restrict__ batch,
                                              float* __restrict__ gsum){
  int nid = blockIdx.x, d = threadIdx.x;
  atomicAdd(&gsum[(size_t)batch[nid]*DC + d], feats[(size_t)nid*DC + d]);
}

__global__ __launch_bounds__(256) void k_gcnt(const int* __restrict__ batch, float* __restrict__ gcnt){
  int i = blockIdx.x*256 + threadIdx.x;
  if (i < N_NODESC) atomicAdd(&gcnt[batch[i]], 1.0f);
}

__global__ __launch_bounds__(256) void k_finalizeH(const float* __restrict__ H_R, const float* __restrict__ gsum,
                                                   const float* __restrict__ gcnt, float* __restrict__ Hrelu){
  int i = blockIdx.x*256 + threadIdx.x;        // < 1088*256
  int row = i >> 8;
  float v;
  if (row < NUM_RC) v = H_R[i];
  else {
    int g = row - NUM_RC;
    v = gsum[i - NUM_RC*DC] / fmaxf(gcnt[g], 1.0f);
  }
  Hrelu[i] = fmaxf(v, 0.0f);
}

// u/z sampling: out[i] = par[row,col] + exp(par[row,256+col]) * N(threefry)
__global__ __launch_bounds__(256) void k_sample(const float* __restrict__ par, float* __restrict__ out,
                                                int row0, int half, uint32_t k0, uint32_t k1){
  int j = blockIdx.x*256 + threadIdx.x;
  if (j >= half) return;
  uint32_t o0, o1;
  tf2x32(k0, k1, (uint32_t)j, (uint32_t)(j + half), &o0, &o1);
  {
    int row = row0 + (j >> 8), col = j & 255;
    out[j] = par[(size_t)row*512 + col] + expf(par[(size_t)row*512 + 256 + col]) * bits_to_normal(o0);
  }
  {
    int i = j + half;
    int row = row0 + (i >> 8), col = i & 255;
    out[i] = par[(size_t)row*512 + col] + expf(par[(size_t)row*512 + 256 + col]) * bits_to_normal(o1);
  }
}

__global__ __launch_bounds__(64) void k_d2(const float* __restrict__ u, float* __restrict__ d2){
  int m = blockIdx.x, r = threadIdx.x;
  const float* um = u + (size_t)(NUM_RC + m)*DC;
  const float* ur = u + (size_t)r*DC;
  float s = 0.f;
  for (int d = 0; d < DC; ++d){ float df = um[d]-ur[d]; s = fmaf(df, df, s); }
  d2[m*NUM_RC + r] = s;
}

__device__ __forceinline__ void A_elem(float* An, const float* d2, int i, uint32_t bits, float inv_s){
  float logp = -0.5f * d2[i] * inv_s;
  float la = logp - logf(fmaxf(-expm1f(logp), 1e-20f));
  float f = bits_to_unit(bits);
  const float mn = 1e-6f, mx = 0.999999f;
  float U = fmaxf(f*(mx-mn) + mn, mn);
  float g = (la + logf(U) - log1pf(-U)) / 0.3f;
  An[i] = 1.0f / (1.0f + expf(-g));
}

__global__ __launch_bounds__(256) void k_A(const float* __restrict__ d2, const float* __restrict__ pg,
                                           float* __restrict__ An, uint32_t k0, uint32_t k1){
  const int HALF = (NUM_MC*NUM_RC)/2;      // 32768
  int j = blockIdx.x*256 + threadIdx.x;
  if (j >= HALF) return;
  uint32_t o0, o1;
  tf2x32(k0, k1, (uint32_t)j, (uint32_t)(j + HALF), &o0, &o1);
  float inv_s = expf(-pg[0]);
  A_elem(An, d2, j, o0, inv_s);
  A_elem(An, d2, j + HALF, o1, inv_s);
}

__global__ __launch_bounds__(64) void k_rownorm(float* __restrict__ An){
  int m = blockIdx.x, r = threadIdx.x;
  float v = An[m*NUM_RC + r];
  float s = waveReduce(v);
  An[m*NUM_RC + r] = v / (s + 1e-8f);
}

__global__ __launch_bounds__(256) void k_logpqz(const float* __restrict__ zM, const float* __restrict__ pzm,
                                                const float* __restrict__ pzl, const float* __restrict__ qz,
                                                float* __restrict__ scal){
  int idx = blockIdx.x*256 + threadIdx.x;   // < 1024*256
  int m = idx >> 8, d = idx & 255;
  float z = zM[idx];
  float pm = pzm[idx], pl = pzl[idx];
  const float* qrow = qz + (size_t)(NUM_RC + m)*512;
  float qm = qrow[d], ql = qrow[256 + d];
  float tp = (z - pm) * expf(-pl);
  float tq = (z - qm) * expf(-ql);
  float term = (-pl - 0.5f*tp*tp) - (-ql - 0.5f*tq*tq);
  float s = waveReduce(term);
  if ((threadIdx.x & 63) == 0) atomicAdd(&scal[0], s);
}

__global__ __launch_bounds__(256) void k_out_head(const float* __restrict__ hid, const float* __restrict__ W2,
                                                  const float* __restrict__ b2, const int* __restrict__ y,
                                                  float* __restrict__ target, int M){
  int wave = threadIdx.x >> 6, lane = threadIdx.x & 63;
  int row = blockIdx.x*4 + wave;
  if (row >= M) return;
  const float* h = hid + (size_t)row*256;
  float p0 = 0.f, p1 = 0.f;
  #pragma unroll
  for (int c = 0; c < 4; c++){
    int d = lane*4 + c;
    float hv = h[d];
    p0 = fmaf(hv, W2[d*2+0], p0);
    p1 = fmaf(hv, W2[d*2+1], p1);
  }
  p0 = waveReduce(p0);
  p1 = waveReduce(p1);
  if (lane == 0){
    float l0 = p0 + b2[0], l1 = p1 + b2[1];
    float mx = fmaxf(l0, l1);
    float lse = mx + logf(expf(l0-mx) + expf(l1-mx));
    float lp = ((y[row] == 0) ? l0 : l1) - lse;
    atomicAdd(target, lp);
  }
}

__global__ __launch_bounds__(256) void k_reg(const float* __restrict__ d2, const int* __restrict__ yM,
                                             float* __restrict__ scal){
  int t = blockIdx.x*256 + threadIdx.x;     // < 32768
  float v = 0.f;
  if (t < 32*1024){
    int i = t >> 10, m = t & 1023;
    int col = i + (1 - yM[m]) * 32;
    v = sqrtf(fmaxf(d2[m*NUM_RC + col], 1e-12f));
  }
  float s = waveReduce(v);
  if ((threadIdx.x & 63) == 0) atomicAdd(&scal[3], s);
}

__global__ void k_final(const float* __restrict__ scal, float* __restrict__ out){
  float pred = -(scal[1] + 0.1f*scal[0]) / 1024.0f;
  float rat  = -scal[2] / 64.0f;
  float regm = scal[3] / 32768.0f;
  out[0] = pred + rat - 0.1f*regm;
}

// ---------------- launch ----------------
extern "C" void kernel_launch(void* const* d_in, const int* in_sizes, int n_in,
                              void* d_out, int out_size, void* d_ws, size_t ws_size,
                              hipStream_t stream) {
  const float* x         = (const float*)d_in[0];
  const int*   edge_index= (const int*)  d_in[1];
  const int*   edge_type = (const int*)  d_in[2];
  const int*   batch     = (const int*)  d_in[3];
  const int*   yM        = (const int*)  d_in[4];
  const int*   yR        = (const int*)  d_in[5];
  const float* H_R       = (const float*)d_in[6];
  const float* node_W    = (const float*)d_in[7];
  const float* node_b    = (const float*)d_in[8];
  const float* gcn_Wr    = (const float*)d_in[9];
  const float* gcn_Wroot = (const float*)d_in[10];
  const float* gcn_b     = (const float*)d_in[11];
  const float* pg_ls     = (const float*)d_in[12];
  const float* pu_W      = (const float*)d_in[13];
  const float* pu_b      = (const float*)d_in[14];
  const float* qz_W      = (const float*)d_in[15];
  const float* qz_b      = (const float*)d_in[16];
  const float* out_W1    = (const float*)d_in[17];
  const float* out_b1    = (const float*)d_in[18];
  const float* out_W2    = (const float*)d_in[19];
  const float* out_b2    = (const float*)d_in[20];
  float* out = (float*)d_out;

  // workspace carve
  char* base = (char*)d_ws;
  size_t off = 0;
  auto ALLOC = [&](size_t nbytes)->void*{
    void* p = base + off; off += (nbytes + 255) & ~(size_t)255; return p;
  };
  float* feats_a = (float*)ALLOC((size_t)N_NODESC*DC*4);
  float* feats_b = (float*)ALLOC((size_t)N_NODESC*DC*4);
  float* tmp     = (float*)ALLOC((size_t)N_NODESC*DC*4);
  float* cnt     = (float*)ALLOC((size_t)N_RELC*N_NODESC*4);
  int*   relmeta = (int*)  ALLOC(64);
  int*   rel_edges=(int*)  ALLOC((size_t)N_EDGESC*4);
  float* gcnt    = (float*)ALLOC(NUM_MC*4);
  float* Hrelu   = (float*)ALLOC((size_t)1088*DC*4);
  float* pu      = (float*)ALLOC((size_t)1088*512*4);
  float* qz      = (float*)ALLOC((size_t)1088*512*4);
  float* u       = (float*)ALLOC((size_t)1088*DC*4);
  float* d2      = (float*)ALLOC((size_t)NUM_MC*NUM_RC*4);
  float* An      = (float*)ALLOC((size_t)NUM_MC*NUM_RC*4);
  float* pzm     = (float*)ALLOC((size_t)NUM_MC*DC*4);
  float* pzl     = (float*)ALLOC((size_t)NUM_MC*DC*4);
  float* zM      = (float*)ALLOC((size_t)NUM_MC*DC*4);
  float* zR      = (float*)ALLOC((size_t)NUM_RC*DC*4);
  float* hidM    = (float*)ALLOC((size_t)NUM_MC*256*4);
  float* hidR    = (float*)ALLOC((size_t)NUM_RC*256*4);
  float* scal    = (float*)ALLOC(64);
  (void)ws_size; (void)in_sizes; (void)n_in; (void)out_size;

  // host-side threefry key derivation: key(42) -> split 4
  uint32_t ya0,ya1,yb0,yb1,yc0,yc1,yd0,yd1;
  tf2x32(0u,42u, 0u,4u, &ya0,&ya1);
  tf2x32(0u,42u, 1u,5u, &yb0,&yb1);
  tf2x32(0u,42u, 2u,6u, &yc0,&yc1);
  tf2x32(0u,42u, 3u,7u, &yd0,&yd1);
  const uint32_t ku0=ya0,  ku1=yb0;   // k_u
  const uint32_t ka0=yc0,  ka1=yd0;   // k_a
  const uint32_t kzm0=ya1, kzm1=yb1;  // k_zm
  const uint32_t kzr0=yc1, kzr1=yd1;  // k_zr

  auto Z = [&](void* p, size_t n){  // n = float count, divisible by 4
    int n4 = (int)(n/4);
    k_zero4<<<dim3((n4+255)/256), dim3(256), 0, stream>>>((float4*)p, n4);
  };
  auto GEMM = [&](const float* A, int lda, const float* B, int ldb, float* C, int ldc,
                  int M, int N, int K, const float* bias, int flags){
    k_gemm<<<dim3(N/64, (M+63)/64), dim3(256), 0, stream>>>(A, lda, B, ldb, C, ldc, M, N, K, bias, flags);
  };

  // ---- setup: counts & relation buckets ----
  Z(cnt, (size_t)N_RELC*N_NODESC);
  Z(relmeta, 16);
  Z(gcnt, NUM_MC);
  Z(scal, 16);
  Z(Hrelu + NUM_RC*DC, (size_t)NUM_MC*DC);   // gsum region
  k_count <<<dim3((N_EDGESC+255)/256), dim3(256), 0, stream>>>(edge_index, edge_type, cnt, relmeta);
  k_prefix<<<dim3(1), dim3(1), 0, stream>>>(relmeta);
  k_fill  <<<dim3((N_EDGESC+255)/256), dim3(256), 0, stream>>>(edge_type, relmeta, rel_edges);

  // ---- input projection: feats = x @ node_W + node_b ----
  GEMM(x, D_INC, node_W, DC, feats_a, DC, N_NODESC, DC, D_INC, node_b, 2);

  // ---- RGCN layers ----
  float* cur = feats_a;
  float* nxt = feats_b;
  for (int l = 0; l < N_LAYERSC; l++){
    GEMM(cur, DC, gcn_Wroot + (size_t)l*DC*DC, DC, nxt, DC, N_NODESC, DC, DC, gcn_b + l*DC, 2);
    for (int r = 0; r < N_RELC; r++){
      Z(tmp, (size_t)N_NODESC*DC);
      k_scatter<<<dim3((N_EDGESC+3)/4), dim3(256), 0, stream>>>(cur, tmp, rel_edges, relmeta, r, edge_index, cnt);
      int fl = 1 | ((l < N_LAYERSC-1 && r == N_RELC-1) ? 4 : 0);
      GEMM(tmp, DC, gcn_Wr + ((size_t)(l*N_RELC + r))*DC*DC, DC, nxt, DC, N_NODESC, DC, DC, nullptr, fl);
    }
    float* t = nxt; nxt = cur; cur = t;
  }
  // cur == final feats (feats_a)

  // ---- graph mean pool + concat + relu ----
  k_gsum<<<dim3(N_NODESC), dim3(DC), 0, stream>>>(cur, batch, Hrelu + NUM_RC*DC);
  k_gcnt<<<dim3((N_NODESC+255)/256), dim3(256), 0, stream>>>(batch, gcnt);
  k_finalizeH<<<dim3(1088), dim3(256), 0, stream>>>(H_R, Hrelu + NUM_RC*DC, gcnt, Hrelu);

  // ---- pu / qz projections ----
  GEMM(Hrelu, DC, pu_W, 512, pu, 512, 1088, 512, DC, pu_b, 2);
  GEMM(Hrelu, DC, qz_W, 512, qz, 512, 1088, 512, DC, qz_b, 2);

  // ---- u sampling ----
  k_sample<<<dim3(544), dim3(256), 0, stream>>>(pu, u, 0, (1088*DC)/2, ku0, ku1);

  // ---- d2, A, An ----
  k_d2<<<dim3(NUM_MC), dim3(64), 0, stream>>>(u, d2);
  k_A <<<dim3(128), dim3(256), 0, stream>>>(d2, pg_ls, An, ka0, ka1);
  k_rownorm<<<dim3(NUM_MC), dim3(64), 0, stream>>>(An);

  // ---- pz = An @ qz[:64] ----
  GEMM(An, NUM_RC, qz,        512, pzm, DC, NUM_MC, DC, NUM_RC, nullptr, 0);
  GEMM(An, NUM_RC, qz + 256,  512, pzl, DC, NUM_MC, DC, NUM_RC, nullptr, 0);

  // ---- z sampling + log_pqz ----
  k_sample<<<dim3(512), dim3(256), 0, stream>>>(qz, zM, NUM_RC, (NUM_MC*DC)/2, kzm0, kzm1);
  k_logpqz<<<dim3(1024), dim3(256), 0, stream>>>(zM, pzm, pzl, qz, scal);
  k_sample<<<dim3(32), dim3(256), 0, stream>>>(qz, zR, 0, (NUM_RC*DC)/2, kzr0, kzr1);

  // ---- output heads (rep = [z, u] handled as split GEMMs) ----
  GEMM(zM, DC, out_W1,          256, hidM, 256, NUM_MC, 256, DC, out_b1, 2);
  GEMM(u + (size_t)NUM_RC*DC, DC, out_W1 + 256*256, 256, hidM, 256, NUM_MC, 256, DC, nullptr, 1|4);
  k_out_head<<<dim3(NUM_MC/4), dim3(256), 0, stream>>>(hidM, out_W2, out_b2, yM, scal+1, NUM_MC);

  GEMM(zR, DC, out_W1,          256, hidR, 256, NUM_RC, 256, DC, out_b1, 2);
  GEMM(u,  DC, out_W1 + 256*256, 256, hidR, 256, NUM_RC, 256, DC, nullptr, 1|4);
  k_out_head<<<dim3(NUM_RC/4), dim3(256), 0, stream>>>(hidR, out_W2, out_b2, yR, scal+2, NUM_RC);

  // ---- reg term & final combine ----
  k_reg<<<dim3(128), dim3(256), 0, stream>>>(d2, yM, scal);
  k_final<<<dim3(1), dim3(1), 0, stream>>>(scal, out);
}

// Round 2
// 3590.028 us; speedup vs baseline: 2.1363x; 2.1363x over previous
//
#include <hip/hip_runtime.h>
#include <stdint.h>

#define N_NODESC 50000
#define N_EDGESC 200000
#define D_INC 128
#define DC 256
#define N_LAYERSC 4
#define N_RELC 4
#define NUM_MC 1024
#define NUM_RC 64

typedef __attribute__((ext_vector_type(4))) float floatx4;
typedef __attribute__((ext_vector_type(8))) short short8;

// ---------------- threefry2x32 (JAX-compatible) ----------------
__host__ __device__ __forceinline__ uint32_t rotl32(uint32_t x, int r){ return (x<<r)|(x>>(32-r)); }

__host__ __device__ inline void tf2x32(uint32_t k0, uint32_t k1, uint32_t x0, uint32_t x1,
                                       uint32_t* o0, uint32_t* o1){
  uint32_t k2 = k0 ^ k1 ^ 0x1BD11BDAu;
#define TFR(r) { x0 += x1; x1 = rotl32(x1, (r)); x1 ^= x0; }
  x0 += k0; x1 += k1;
  TFR(13) TFR(15) TFR(26) TFR(6)
  x0 += k1; x1 += k2 + 1u;
  TFR(17) TFR(29) TFR(16) TFR(24)
  x0 += k2; x1 += k0 + 2u;
  TFR(13) TFR(15) TFR(26) TFR(6)
  x0 += k0; x1 += k1 + 3u;
  TFR(17) TFR(29) TFR(16) TFR(24)
  x0 += k1; x1 += k2 + 4u;
  TFR(13) TFR(15) TFR(26) TFR(6)
  x0 += k2; x1 += k0 + 5u;
#undef TFR
  *o0 = x0; *o1 = x1;
}

__device__ __forceinline__ float erfinv_f32(float x){
  float w = -log1pf(-x*x);
  float p;
  if (w < 5.0f){
    w -= 2.5f;
    p = 2.81022636e-08f;
    p = fmaf(p, w, 3.43273939e-07f);
    p = fmaf(p, w, -3.5233877e-06f);
    p = fmaf(p, w, -4.39150654e-06f);
    p = fmaf(p, w, 0.00021858087f);
    p = fmaf(p, w, -0.00125372503f);
    p = fmaf(p, w, -0.00417768164f);
    p = fmaf(p, w, 0.246640727f);
    p = fmaf(p, w, 1.50140941f);
  } else {
    w = sqrtf(w) - 3.0f;
    p = -0.000200214257f;
    p = fmaf(p, w, 0.000100950558f);
    p = fmaf(p, w, 0.00134934322f);
    p = fmaf(p, w, -0.00367342844f);
    p = fmaf(p, w, 0.00573950773f);
    p = fmaf(p, w, -0.0076224613f);
    p = fmaf(p, w, 0.00943887047f);
    p = fmaf(p, w, 1.00167406f);
    p = fmaf(p, w, 2.83297682f);
  }
  return p*x;
}

__device__ __forceinline__ float bits_to_unit(uint32_t b){
  return __uint_as_float((b >> 9) | 0x3f800000u) - 1.0f;
}

__device__ __forceinline__ float bits_to_normal(uint32_t b){
  float f = bits_to_unit(b);
  const float lo = -0.99999994f;
  float u = f * (1.0f - lo) + lo;
  u = fmaxf(u, lo);
  return 1.41421356f * erfinv_f32(u);
}

__device__ __forceinline__ float waveReduce(float v){
  #pragma unroll
  for (int m = 1; m < 64; m <<= 1) v += __shfl_xor(v, m, 64);
  return v;
}

__device__ __forceinline__ ushort f2bf(float f){
  uint32_t u = __float_as_uint(f);
  uint32_t r = u + 0x7fffu + ((u>>16)&1u);
  return (ushort)(r>>16);
}
__device__ __forceinline__ float bf2f(ushort h){
  return __uint_as_float(((uint32_t)h)<<16);
}

typedef const __attribute__((address_space(1))) void* gas_t;
typedef __attribute__((address_space(3))) void* las_t;
__device__ __forceinline__ void gld16(const void* g, void* l){
  __builtin_amdgcn_global_load_lds((gas_t)g, (las_t)l, 16, 0, 0);
}

// ---------------- utility kernels ----------------
__global__ __launch_bounds__(256) void k_zero4(float4* p, int n4){
  int i = blockIdx.x*256 + threadIdx.x;
  if (i < n4) p[i] = make_float4(0.f,0.f,0.f,0.f);
}

__global__ __launch_bounds__(256) void k_count(const int* __restrict__ ei, const int* __restrict__ et,
                                               float* __restrict__ cnt){
  int e = blockIdx.x*256 + threadIdx.x;
  if (e >= N_EDGESC) return;
  atomicAdd(&cnt[(size_t)et[e]*N_NODESC + ei[N_EDGESC + e]], 1.0f);
}

// weight transpose+convert: dst[mat][n][k] = bf16(src[mat][k][n])
__global__ __launch_bounds__(256) void k_wt(const float* __restrict__ src, ushort* __restrict__ dst,
                                            int K, int N, int total){
  int idx = blockIdx.x*256 + threadIdx.x;
  if (idx >= total) return;
  int kn = K*N;
  int mat = idx / kn, rem = idx - mat*kn;
  int k = rem / N, n = rem - k*N;
  dst[(size_t)mat*kn + (size_t)n*K + k] = f2bf(src[idx]);
}

// float4 -> 4x bf16, optional relu
__global__ __launch_bounds__(256) void k_cvt4(const float4* __restrict__ src, ushort4* __restrict__ dst,
                                              int n4, int relu){
  int i = blockIdx.x*256 + threadIdx.x;
  if (i >= n4) return;
  float4 v = src[i];
  if (relu){ v.x=fmaxf(v.x,0.f); v.y=fmaxf(v.y,0.f); v.z=fmaxf(v.z,0.f); v.w=fmaxf(v.w,0.f); }
  ushort4 o; o.x=f2bf(v.x); o.y=f2bf(v.y); o.z=f2bf(v.z); o.w=f2bf(v.w);
  dst[i] = o;
}

// one wave per edge: nxt[dst] += bf16(hrel[et[e]][src]) * invc
__global__ __launch_bounds__(256) void k_scatter2(const ushort* __restrict__ hrel, float* __restrict__ nxt,
                                                  const int* __restrict__ ei, const int* __restrict__ et,
                                                  const float* __restrict__ cnt){
  int e = blockIdx.x*4 + (threadIdx.x >> 6);
  if (e >= N_EDGESC) return;
  int lane = threadIdx.x & 63;
  int src = ei[e], dst = ei[N_EDGESC + e], r = et[e];
  float invc = 1.0f / fmaxf(cnt[(size_t)r*N_NODESC + dst], 1.0f);
  const ushort4 h = *(const ushort4*)(hrel + ((size_t)r*N_NODESC + src)*DC + lane*4);
  float* tp = nxt + (size_t)dst*DC + lane*4;
  atomicAdd(tp+0, bf2f(h.x)*invc);
  atomicAdd(tp+1, bf2f(h.y)*invc);
  atomicAdd(tp+2, bf2f(h.z)*invc);
  atomicAdd(tp+3, bf2f(h.w)*invc);
}

// ---------------- bf16 MFMA GEMM: C = A[M,K] @ Bt[N,K]^T (+bias) ------------
// flags: 1 = output bf16, 2 = add bias. N multiple of 128, K multiple of 32.
__global__ __launch_bounds__(256) void k_gemm_bf16(
    const ushort* __restrict__ A, int lda,
    const ushort* __restrict__ Bt0, int ldb,
    void* __restrict__ Cout0, int ldc,
    int M, int N, int K,
    const float* __restrict__ bias, int flags,
    size_t strideB, size_t strideC)
{
  __shared__ ushort As[128*32];
  __shared__ ushort Bs[128*32];
  const int tid = threadIdx.x;
  const int wave = tid >> 6, lane = tid & 63;
  const int m0 = blockIdx.y * 128, n0 = blockIdx.x * 128;
  const ushort* Bt = Bt0 + blockIdx.z * strideB;
  const int wm = (wave >> 1) * 64, wn = (wave & 1) * 64;
  const int qa = lane >> 4, lm = lane & 15;

  // staging geometry: wave handles rows [wave*32, wave*32+32) in two 16-row chunks
  const int srow = wave*32 + (lane >> 2);
  const int scol = (lane & 3) * 8;

  floatx4 acc[4][4] = {};

  for (int k0 = 0; k0 < K; k0 += 32){
    {
      int r1 = m0 + srow;      if (r1 > M-1) r1 = M-1;
      int r2 = m0 + srow + 16; if (r2 > M-1) r2 = M-1;
      gld16(A + (size_t)r1*lda + k0 + scol, (char*)As + (size_t)srow*64 + (lane&3)*16);
      gld16(A + (size_t)r2*lda + k0 + scol, (char*)As + (size_t)(srow+16)*64 + (lane&3)*16);
      gld16(Bt + (size_t)(n0 + srow)*ldb + k0 + scol,      (char*)Bs + (size_t)srow*64 + (lane&3)*16);
      gld16(Bt + (size_t)(n0 + srow + 16)*ldb + k0 + scol, (char*)Bs + (size_t)(srow+16)*64 + (lane&3)*16);
    }
    __syncthreads();
    short8 af[4], bfv[4];
    #pragma unroll
    for (int mt = 0; mt < 4; mt++)
      af[mt] = *(const short8*)(As + (size_t)(wm + mt*16 + lm)*32 + qa*8);
    #pragma unroll
    for (int nt = 0; nt < 4; nt++)
      bfv[nt] = *(const short8*)(Bs + (size_t)(wn + nt*16 + lm)*32 + qa*8);
    #pragma unroll
    for (int mt = 0; mt < 4; mt++)
      #pragma unroll
      for (int nt = 0; nt < 4; nt++)
        acc[mt][nt] = __builtin_amdgcn_mfma_f32_16x16x32_bf16(af[mt], bfv[nt], acc[mt][nt], 0, 0, 0);
    __syncthreads();
  }

  // epilogue: C/D layout col=lane&15, row=(lane>>4)*4+i
  char* Cout = (char*)Cout0;
  #pragma unroll
  for (int mt = 0; mt < 4; mt++){
    #pragma unroll
    for (int i = 0; i < 4; i++){
      int row = m0 + wm + mt*16 + qa*4 + i;
      if (row >= M) continue;
      #pragma unroll
      for (int nt = 0; nt < 4; nt++){
        int col = n0 + wn + nt*16 + lm;
        float v = acc[mt][nt][i];
        if (flags & 2) v += bias[col];
        if (flags & 1)
          ((ushort*)Cout)[blockIdx.z*strideC + (size_t)row*ldc + col] = f2bf(v);
        else
          ((float*)Cout)[blockIdx.z*strideC + (size_t)row*ldc + col] = v;
      }
    }
  }
}

// ---------------- fp32 GEMM (small matrices): C(+)= A@B (+bias)(relu) -------
__global__ __launch_bounds__(256) void k_gemm(
    const float* __restrict__ A, int lda,
    const float* __restrict__ B, int ldb,
    float* __restrict__ C, int ldc,
    int M, int N, int K,
    const float* __restrict__ bias, int flags)
{
  __shared__ __align__(16) float Asm[64][36];
  __shared__ __align__(16) float Bsm[32][64];
  const int tid = threadIdx.x;
  const int tx = tid & 15, ty = tid >> 4;
  const int m0 = blockIdx.y * 64, n0 = blockIdx.x * 64;
  const int am = tid >> 2, ak = (tid & 3) * 8;
  const int bk = tid >> 3, bn = (tid & 7) * 8;
  float acc[4][4] = {};
  for (int k0 = 0; k0 < K; k0 += 32){
    float4 a0, a1;
    int arow = m0 + am;
    if (arow < M){
      const float* ap = A + (size_t)arow*lda + (k0 + ak);
      a0 = *(const float4*)ap;
      a1 = *(const float4*)(ap + 4);
    } else {
      a0 = make_float4(0,0,0,0); a1 = a0;
    }
    const float* bp = B + (size_t)(k0 + bk)*ldb + (n0 + bn);
    float4 b0v = *(const float4*)bp;
    float4 b1v = *(const float4*)(bp + 4);
    *(float4*)&Asm[am][ak]   = a0;
    *(float4*)&Asm[am][ak+4] = a1;
    *(float4*)&Bsm[bk][bn]   = b0v;
    *(float4*)&Bsm[bk][bn+4] = b1v;
    __syncthreads();
    #pragma unroll
    for (int kk = 0; kk < 32; ++kk){
      float av[4], bv[4];
      #pragma unroll
      for (int i=0;i<4;i++) av[i] = Asm[ty*4+i][kk];
      #pragma unroll
      for (int j=0;j<4;j++) bv[j] = Bsm[kk][tx*4+j];
      #pragma unroll
      for (int i=0;i<4;i++)
        #pragma unroll
        for (int j=0;j<4;j++)
          acc[i][j] = fmaf(av[i], bv[j], acc[i][j]);
    }
    __syncthreads();
  }
  #pragma unroll
  for (int i=0;i<4;i++){
    int row = m0 + ty*4 + i;
    if (row >= M) continue;
    #pragma unroll
    for (int j=0;j<4;j++){
      int col = n0 + tx*4 + j;
      float v = acc[i][j];
      if (flags & 2) v += bias[col];
      if (flags & 1) v += C[(size_t)row*ldc + col];
      if (flags & 4) v = fmaxf(v, 0.0f);
      C[(size_t)row*ldc + col] = v;
    }
  }
}

// ---------------- pooling & head kernels ----------------
__global__ __launch_bounds__(256) void k_gsum(const float* __restrict__ feats, const int* __restrict__ batch,
                                              float* __restrict__ gsum){
  int nid = blockIdx.x, d = threadIdx.x;
  atomicAdd(&gsum[(size_t)batch[nid]*DC + d], feats[(size_t)nid*DC + d]);
}

__global__ __launch_bounds__(256) void k_gcnt(const int* __restrict__ batch, float* __restrict__ gcnt){
  int i = blockIdx.x*256 + threadIdx.x;
  if (i < N_NODESC) atomicAdd(&gcnt[batch[i]], 1.0f);
}

__global__ __launch_bounds__(256) void k_finalizeH(const float* __restrict__ H_R, const float* __restrict__ gsum,
                                                   const float* __restrict__ gcnt, float* __restrict__ Hrelu){
  int i = blockIdx.x*256 + threadIdx.x;
  int row = i >> 8;
  float v;
  if (row < NUM_RC) v = H_R[i];
  else {
    int g = row - NUM_RC;
    v = gsum[i - NUM_RC*DC] / fmaxf(gcnt[g], 1.0f);
  }
  Hrelu[i] = fmaxf(v, 0.0f);
}

__global__ __launch_bounds__(256) void k_sample(const float* __restrict__ par, float* __restrict__ out,
                                                int row0, int half, uint32_t k0, uint32_t k1){
  int j = blockIdx.x*256 + threadIdx.x;
  if (j >= half) return;
  uint32_t o0, o1;
  tf2x32(k0, k1, (uint32_t)j, (uint32_t)(j + half), &o0, &o1);
  {
    int row = row0 + (j >> 8), col = j & 255;
    out[j] = par[(size_t)row*512 + col] + expf(par[(size_t)row*512 + 256 + col]) * bits_to_normal(o0);
  }
  {
    int i = j + half;
    int row = row0 + (i >> 8), col = i & 255;
    out[i] = par[(size_t)row*512 + col] + expf(par[(size_t)row*512 + 256 + col]) * bits_to_normal(o1);
  }
}

__global__ __launch_bounds__(64) void k_d2(const float* __restrict__ u, float* __restrict__ d2){
  int m = blockIdx.x, r = threadIdx.x;
  const float* um = u + (size_t)(NUM_RC + m)*DC;
  const float* ur = u + (size_t)r*DC;
  float s = 0.f;
  for (int d = 0; d < DC; ++d){ float df = um[d]-ur[d]; s = fmaf(df, df, s); }
  d2[m*NUM_RC + r] = s;
}

__device__ __forceinline__ void A_elem(float* An, const float* d2, int i, uint32_t bits, float inv_s){
  float logp = -0.5f * d2[i] * inv_s;
  float la = logp - logf(fmaxf(-expm1f(logp), 1e-20f));
  float f = bits_to_unit(bits);
  const float mn = 1e-6f, mx = 0.999999f;
  float U = fmaxf(f*(mx-mn) + mn, mn);
  float g = (la + logf(U) - log1pf(-U)) / 0.3f;
  An[i] = 1.0f / (1.0f + expf(-g));
}

__global__ __launch_bounds__(256) void k_A(const float* __restrict__ d2, const float* __restrict__ pg,
                                           float* __restrict__ An, uint32_t k0, uint32_t k1){
  const int HALF = (NUM_MC*NUM_RC)/2;
  int j = blockIdx.x*256 + threadIdx.x;
  if (j >= HALF) return;
  uint32_t o0, o1;
  tf2x32(k0, k1, (uint32_t)j, (uint32_t)(j + HALF), &o0, &o1);
  float inv_s = expf(-pg[0]);
  A_elem(An, d2, j, o0, inv_s);
  A_elem(An, d2, j + HALF, o1, inv_s);
}

__global__ __launch_bounds__(64) void k_rownorm(float* __restrict__ An){
  int m = blockIdx.x, r = threadIdx.x;
  float v = An[m*NUM_RC + r];
  float s = waveReduce(v);
  An[m*NUM_RC + r] = v / (s + 1e-8f);
}

__global__ __launch_bounds__(256) void k_logpqz(const float* __restrict__ zM, const float* __restrict__ pzm,
                                                const float* __restrict__ pzl, const float* __restrict__ qz,
                                                float* __restrict__ scal){
  int idx = blockIdx.x*256 + threadIdx.x;
  int m = idx >> 8, d = idx & 255;
  float z = zM[idx];
  float pm = pzm[idx], pl = pzl[idx];
  const float* qrow = qz + (size_t)(NUM_RC + m)*512;
  float qm = qrow[d], ql = qrow[256 + d];
  float tp = (z - pm) * expf(-pl);
  float tq = (z - qm) * expf(-ql);
  float term = (-pl - 0.5f*tp*tp) - (-ql - 0.5f*tq*tq);
  float s = waveReduce(term);
  if ((threadIdx.x & 63) == 0) atomicAdd(&scal[0], s);
}

__global__ __launch_bounds__(256) void k_out_head(const float* __restrict__ hid, const float* __restrict__ W2,
                                                  const float* __restrict__ b2, const int* __restrict__ y,
                                                  float* __restrict__ target, int M){
  int wave = threadIdx.x >> 6, lane = threadIdx.x & 63;
  int row = blockIdx.x*4 + wave;
  if (row >= M) return;
  const float* h = hid + (size_t)row*256;
  float p0 = 0.f, p1 = 0.f;
  #pragma unroll
  for (int c = 0; c < 4; c++){
    int d = lane*4 + c;
    float hv = h[d];
    p0 = fmaf(hv, W2[d*2+0], p0);
    p1 = fmaf(hv, W2[d*2+1], p1);
  }
  p0 = waveReduce(p0);
  p1 = waveReduce(p1);
  if (lane == 0){
    float l0 = p0 + b2[0], l1 = p1 + b2[1];
    float mx = fmaxf(l0, l1);
    float lse = mx + logf(expf(l0-mx) + expf(l1-mx));
    float lp = ((y[row] == 0) ? l0 : l1) - lse;
    atomicAdd(target, lp);
  }
}

__global__ __launch_bounds__(256) void k_reg(const float* __restrict__ d2, const int* __restrict__ yM,
                                             float* __restrict__ scal){
  int t = blockIdx.x*256 + threadIdx.x;
  float v = 0.f;
  if (t < 32*1024){
    int i = t >> 10, m = t & 1023;
    int col = i + (1 - yM[m]) * 32;
    v = sqrtf(fmaxf(d2[m*NUM_RC + col], 1e-12f));
  }
  float s = waveReduce(v);
  if ((threadIdx.x & 63) == 0) atomicAdd(&scal[3], s);
}

__global__ void k_final(const float* __restrict__ scal, float* __restrict__ out){
  float pred = -(scal[1] + 0.1f*scal[0]) / 1024.0f;
  float rat  = -scal[2] / 64.0f;
  float regm = scal[3] / 32768.0f;
  out[0] = pred + rat - 0.1f*regm;
}

// ---------------- launch ----------------
extern "C" void kernel_launch(void* const* d_in, const int* in_sizes, int n_in,
                              void* d_out, int out_size, void* d_ws, size_t ws_size,
                              hipStream_t stream) {
  const float* x         = (const float*)d_in[0];
  const int*   edge_index= (const int*)  d_in[1];
  const int*   edge_type = (const int*)  d_in[2];
  const int*   batch     = (const int*)  d_in[3];
  const int*   yM        = (const int*)  d_in[4];
  const int*   yR        = (const int*)  d_in[5];
  const float* H_R       = (const float*)d_in[6];
  const float* node_W    = (const float*)d_in[7];
  const float* node_b    = (const float*)d_in[8];
  const float* gcn_Wr    = (const float*)d_in[9];
  const float* gcn_Wroot = (const float*)d_in[10];
  const float* gcn_b     = (const float*)d_in[11];
  const float* pg_ls     = (const float*)d_in[12];
  const float* pu_W      = (const float*)d_in[13];
  const float* pu_b      = (const float*)d_in[14];
  const float* qz_W      = (const float*)d_in[15];
  const float* qz_b      = (const float*)d_in[16];
  const float* out_W1    = (const float*)d_in[17];
  const float* out_b1    = (const float*)d_in[18];
  const float* out_W2    = (const float*)d_in[19];
  const float* out_b2    = (const float*)d_in[20];
  float* out = (float*)d_out;

  char* base = (char*)d_ws;
  size_t off = 0;
  auto ALLOC = [&](size_t nbytes)->void*{
    void* p = base + off; off += (nbytes + 255) & ~(size_t)255; return p;
  };
  float*  nxt      = (float*) ALLOC((size_t)N_NODESC*DC*4);          // fp32 feats accumulator
  ushort* curb     = (ushort*)ALLOC((size_t)N_NODESC*DC*2);          // bf16 feats
  ushort* hrel     = (ushort*)ALLOC((size_t)N_RELC*N_NODESC*DC*2);   // bf16 per-rel transform
  ushort* xb       = (ushort*)ALLOC((size_t)N_NODESC*D_INC*2);       // bf16 x
  ushort* node_Wt  = (ushort*)ALLOC((size_t)DC*D_INC*2);
  ushort* Wroot_t  = (ushort*)ALLOC((size_t)N_LAYERSC*DC*DC*2);
  ushort* Wr_t     = (ushort*)ALLOC((size_t)N_LAYERSC*N_RELC*DC*DC*2);
  float*  cnt      = (float*) ALLOC((size_t)N_RELC*N_NODESC*4);
  float*  gcnt     = (float*) ALLOC(NUM_MC*4);
  float*  Hrelu    = (float*) ALLOC((size_t)1088*DC*4);
  float*  pu       = (float*) ALLOC((size_t)1088*512*4);
  float*  qz       = (float*) ALLOC((size_t)1088*512*4);
  float*  u        = (float*) ALLOC((size_t)1088*DC*4);
  float*  d2      = (float*)  ALLOC((size_t)NUM_MC*NUM_RC*4);
  float*  An      = (float*)  ALLOC((size_t)NUM_MC*NUM_RC*4);
  float*  pzm     = (float*)  ALLOC((size_t)NUM_MC*DC*4);
  float*  pzl     = (float*)  ALLOC((size_t)NUM_MC*DC*4);
  float*  zM      = (float*)  ALLOC((size_t)NUM_MC*DC*4);
  float*  zR      = (float*)  ALLOC((size_t)NUM_RC*DC*4);
  float*  hidM    = (float*)  ALLOC((size_t)NUM_MC*256*4);
  float*  hidR    = (float*)  ALLOC((size_t)NUM_RC*256*4);
  float*  scal    = (float*)  ALLOC(64);
  (void)ws_size; (void)in_sizes; (void)n_in; (void)out_size;

  uint32_t ya0,ya1,yb0,yb1,yc0,yc1,yd0,yd1;
  tf2x32(0u,42u, 0u,4u, &ya0,&ya1);
  tf2x32(0u,42u, 1u,5u, &yb0,&yb1);
  tf2x32(0u,42u, 2u,6u, &yc0,&yc1);
  tf2x32(0u,42u, 3u,7u, &yd0,&yd1);
  const uint32_t ku0=ya0,  ku1=yb0;
  const uint32_t ka0=yc0,  ka1=yd0;
  const uint32_t kzm0=ya1, kzm1=yb1;
  const uint32_t kzr0=yc1, kzr1=yd1;

  auto Z = [&](void* p, size_t n){
    int n4 = (int)(n/4);
    k_zero4<<<dim3((n4+255)/256), dim3(256), 0, stream>>>((float4*)p, n4);
  };
  auto GEMM = [&](const float* A, int lda, const float* B, int ldb, float* C, int ldc,
                  int M, int N, int K, const float* bias, int flags){
    k_gemm<<<dim3(N/64, (M+63)/64), dim3(256), 0, stream>>>(A, lda, B, ldb, C, ldc, M, N, K, bias, flags);
  };
  auto BGEMM = [&](const ushort* A, int lda, const ushort* Bt, int ldb, void* C, int ldc,
                   int M, int N, int K, const float* bias, int flags, int gz,
                   size_t strideB, size_t strideC){
    k_gemm_bf16<<<dim3(N/128, (M+127)/128, gz), dim3(256), 0, stream>>>(
        A, lda, Bt, ldb, C, ldc, M, N, K, bias, flags, strideB, strideC);
  };

  // ---- setup ----
  Z(cnt, (size_t)N_RELC*N_NODESC);
  Z(gcnt, NUM_MC);
  Z(scal, 16);
  Z(Hrelu + NUM_RC*DC, (size_t)NUM_MC*DC);   // gsum region
  k_count<<<dim3((N_EDGESC+255)/256), dim3(256), 0, stream>>>(edge_index, edge_type, cnt);

  // weight prep (transpose + bf16)
  {
    int t1 = D_INC*DC;
    k_wt<<<dim3((t1+255)/256), dim3(256), 0, stream>>>(node_W, node_Wt, D_INC, DC, t1);
    int t2 = N_LAYERSC*DC*DC;
    k_wt<<<dim3((t2+255)/256), dim3(256), 0, stream>>>(gcn_Wroot, Wroot_t, DC, DC, t2);
    int t3 = N_LAYERSC*N_RELC*DC*DC;
    k_wt<<<dim3((t3+255)/256), dim3(256), 0, stream>>>(gcn_Wr, Wr_t, DC, DC, t3);
    int n4 = (N_NODESC*D_INC)/4;
    k_cvt4<<<dim3((n4+255)/256), dim3(256), 0, stream>>>((const float4*)x, (ushort4*)xb, n4, 0);
  }

  // ---- input projection: curb = bf16(x @ node_W + node_b) ----
  BGEMM(xb, D_INC, node_Wt, D_INC, curb, DC, N_NODESC, DC, D_INC, node_b, 1|2, 1, 0, 0);

  // ---- RGCN layers (transform-then-aggregate) ----
  for (int l = 0; l < N_LAYERSC; l++){
    // nxt = curb @ Wroot + b   (fp32 out)
    BGEMM(curb, DC, Wroot_t + (size_t)l*DC*DC, DC, nxt, DC, N_NODESC, DC, DC, gcn_b + l*DC, 2, 1, 0, 0);
    // hrel[r] = curb @ Wr[l,r]  (bf16 out, batched over r)
    BGEMM(curb, DC, Wr_t + (size_t)l*N_RELC*DC*DC, DC, hrel, DC, N_NODESC, DC, DC, nullptr, 1, N_RELC,
          (size_t)DC*DC, (size_t)N_NODESC*DC);
    // scatter: nxt[dst] += hrel[et][src]/cnt
    k_scatter2<<<dim3((N_EDGESC+3)/4), dim3(256), 0, stream>>>(hrel, nxt, edge_index, edge_type, cnt);
    if (l < N_LAYERSC-1){
      int n4 = (N_NODESC*DC)/4;
      k_cvt4<<<dim3((n4+255)/256), dim3(256), 0, stream>>>((const float4*)nxt, (ushort4*)curb, n4, 1);
    }
  }
  // nxt == final feats (fp32, no relu)

  // ---- graph mean pool + concat + relu ----
  k_gsum<<<dim3(N_NODESC), dim3(DC), 0, stream>>>(nxt, batch, Hrelu + NUM_RC*DC);
  k_gcnt<<<dim3((N_NODESC+255)/256), dim3(256), 0, stream>>>(batch, gcnt);
  k_finalizeH<<<dim3(1088), dim3(256), 0, stream>>>(H_R, Hrelu + NUM_RC*DC, gcnt, Hrelu);

  // ---- pu / qz projections (fp32) ----
  GEMM(Hrelu, DC, pu_W, 512, pu, 512, 1088, 512, DC, pu_b, 2);
  GEMM(Hrelu, DC, qz_W, 512, qz, 512, 1088, 512, DC, qz_b, 2);

  // ---- u sampling ----
  k_sample<<<dim3(544), dim3(256), 0, stream>>>(pu, u, 0, (1088*DC)/2, ku0, ku1);

  // ---- d2, A, An ----
  k_d2<<<dim3(NUM_MC), dim3(64), 0, stream>>>(u, d2);
  k_A <<<dim3(128), dim3(256), 0, stream>>>(d2, pg_ls, An, ka0, ka1);
  k_rownorm<<<dim3(NUM_MC), dim3(64), 0, stream>>>(An);

  // ---- pz = An @ qz[:64] ----
  GEMM(An, NUM_RC, qz,        512, pzm, DC, NUM_MC, DC, NUM_RC, nullptr, 0);
  GEMM(An, NUM_RC, qz + 256,  512, pzl, DC, NUM_MC, DC, NUM_RC, nullptr, 0);

  // ---- z sampling + log_pqz ----
  k_sample<<<dim3(512), dim3(256), 0, stream>>>(qz, zM, NUM_RC, (NUM_MC*DC)/2, kzm0, kzm1);
  k_logpqz<<<dim3(1024), dim3(256), 0, stream>>>(zM, pzm, pzl, qz, scal);
  k_sample<<<dim3(32), dim3(256), 0, stream>>>(qz, zR, 0, (NUM_RC*DC)/2, kzr0, kzr1);

  // ---- output heads ----
  GEMM(zM, DC, out_W1,           256, hidM, 256, NUM_MC, 256, DC, out_b1, 2);
  GEMM(u + (size_t)NUM_RC*DC, DC, out_W1 + 256*256, 256, hidM, 256, NUM_MC, 256, DC, nullptr, 1|4);
  k_out_head<<<dim3(NUM_MC/4), dim3(256), 0, stream>>>(hidM, out_W2, out_b2, yM, scal+1, NUM_MC);

  GEMM(zR, DC, out_W1,           256, hidR, 256, NUM_RC, 256, DC, out_b1, 2);
  GEMM(u,  DC, out_W1 + 256*256, 256, hidR, 256, NUM_RC, 256, DC, nullptr, 1|4);
  k_out_head<<<dim3(NUM_RC/4), dim3(256), 0, stream>>>(hidR, out_W2, out_b2, yR, scal+2, NUM_RC);

  // ---- reg term & final combine ----
  k_reg<<<dim3(128), dim3(256), 0, stream>>>(d2, yM, scal);
  k_final<<<dim3(1), dim3(1), 0, stream>>>(scal, out);
}

// Round 3
// 1087.808 us; speedup vs baseline: 7.0502x; 3.3002x over previous
//
#include <hip/hip_runtime.h>
#include <stdint.h>

#define N_NODESC 50000
#define N_EDGESC 200000
#define D_INC 128
#define DC 256
#define N_LAYERSC 4
#define N_RELC 4
#define NUM_MC 1024
#define NUM_RC 64

typedef __attribute__((ext_vector_type(4))) float floatx4;
typedef __attribute__((ext_vector_type(8))) short short8;

// ---------------- threefry2x32 (JAX-compatible) ----------------
__host__ __device__ __forceinline__ uint32_t rotl32(uint32_t x, int r){ return (x<<r)|(x>>(32-r)); }

__host__ __device__ inline void tf2x32(uint32_t k0, uint32_t k1, uint32_t x0, uint32_t x1,
                                       uint32_t* o0, uint32_t* o1){
  uint32_t k2 = k0 ^ k1 ^ 0x1BD11BDAu;
#define TFR(r) { x0 += x1; x1 = rotl32(x1, (r)); x1 ^= x0; }
  x0 += k0; x1 += k1;
  TFR(13) TFR(15) TFR(26) TFR(6)
  x0 += k1; x1 += k2 + 1u;
  TFR(17) TFR(29) TFR(16) TFR(24)
  x0 += k2; x1 += k0 + 2u;
  TFR(13) TFR(15) TFR(26) TFR(6)
  x0 += k0; x1 += k1 + 3u;
  TFR(17) TFR(29) TFR(16) TFR(24)
  x0 += k1; x1 += k2 + 4u;
  TFR(13) TFR(15) TFR(26) TFR(6)
  x0 += k2; x1 += k0 + 5u;
#undef TFR
  *o0 = x0; *o1 = x1;
}

__device__ __forceinline__ float erfinv_f32(float x){
  float w = -log1pf(-x*x);
  float p;
  if (w < 5.0f){
    w -= 2.5f;
    p = 2.81022636e-08f;
    p = fmaf(p, w, 3.43273939e-07f);
    p = fmaf(p, w, -3.5233877e-06f);
    p = fmaf(p, w, -4.39150654e-06f);
    p = fmaf(p, w, 0.00021858087f);
    p = fmaf(p, w, -0.00125372503f);
    p = fmaf(p, w, -0.00417768164f);
    p = fmaf(p, w, 0.246640727f);
    p = fmaf(p, w, 1.50140941f);
  } else {
    w = sqrtf(w) - 3.0f;
    p = -0.000200214257f;
    p = fmaf(p, w, 0.000100950558f);
    p = fmaf(p, w, 0.00134934322f);
    p = fmaf(p, w, -0.00367342844f);
    p = fmaf(p, w, 0.00573950773f);
    p = fmaf(p, w, -0.0076224613f);
    p = fmaf(p, w, 0.00943887047f);
    p = fmaf(p, w, 1.00167406f);
    p = fmaf(p, w, 2.83297682f);
  }
  return p*x;
}

__device__ __forceinline__ float bits_to_unit(uint32_t b){
  return __uint_as_float((b >> 9) | 0x3f800000u) - 1.0f;
}

__device__ __forceinline__ float bits_to_normal(uint32_t b){
  float f = bits_to_unit(b);
  const float lo = -0.99999994f;
  float u = f * (1.0f - lo) + lo;
  u = fmaxf(u, lo);
  return 1.41421356f * erfinv_f32(u);
}

__device__ __forceinline__ float waveReduce(float v){
  #pragma unroll
  for (int m = 1; m < 64; m <<= 1) v += __shfl_xor(v, m, 64);
  return v;
}

__device__ __forceinline__ ushort f2bf(float f){
  uint32_t u = __float_as_uint(f);
  uint32_t r = u + 0x7fffu + ((u>>16)&1u);
  return (ushort)(r>>16);
}
__device__ __forceinline__ float bf2f(ushort h){
  return __uint_as_float(((uint32_t)h)<<16);
}

typedef const __attribute__((address_space(1))) void* gas_t;
typedef __attribute__((address_space(3))) void* las_t;
__device__ __forceinline__ void gld16(const void* g, void* l){
  __builtin_amdgcn_global_load_lds((gas_t)g, (las_t)l, 16, 0, 0);
}

// ---------------- utility kernels ----------------
__global__ __launch_bounds__(256) void k_zero4(float4* p, int n4){
  int i = blockIdx.x*256 + threadIdx.x;
  if (i < n4) p[i] = make_float4(0.f,0.f,0.f,0.f);
}

// deg[dst]++, cnt[r,dst]++
__global__ __launch_bounds__(256) void k_count(const int* __restrict__ ei, const int* __restrict__ et,
                                               float* __restrict__ cnt, int* __restrict__ deg){
  int e = blockIdx.x*256 + threadIdx.x;
  if (e >= N_EDGESC) return;
  int r = et[e], dstv = ei[N_EDGESC + e];
  atomicAdd(&cnt[(size_t)r*N_NODESC + dstv], 1.0f);
  atomicAdd(&deg[dstv], 1);
}

// exclusive scan over deg[0..N), rowptr[N]=total. one block, 256 threads.
__global__ __launch_bounds__(256) void k_scan(const int* __restrict__ deg, int* __restrict__ rowptr){
  __shared__ int part[256];
  const int n = N_NODESC, t = threadIdx.x;
  const int chunk = (n + 255) / 256;
  int lo = t*chunk, hi = lo + chunk; if (hi > n) hi = n;
  int s = 0;
  for (int i = lo; i < hi; i++) s += deg[i];
  part[t] = s;
  __syncthreads();
  if (t == 0){
    int run = 0;
    for (int i = 0; i < 256; i++){ int v = part[i]; part[i] = run; run += v; }
  }
  __syncthreads();
  int off = part[t];
  for (int i = lo; i < hi; i++){ rowptr[i] = off; off += deg[i]; }
  if (t == 255) rowptr[n] = off;
}

// fill CSR: ep[pos] = src | (rel<<16); einvc[pos] = 1/max(cnt[r,dst],1)
__global__ __launch_bounds__(256) void k_fill2(const int* __restrict__ ei, const int* __restrict__ et,
                                               const float* __restrict__ cnt, const int* __restrict__ rowptr,
                                               int* __restrict__ cursor, int* __restrict__ ep,
                                               float* __restrict__ einvc){
  int e = blockIdx.x*256 + threadIdx.x;
  if (e >= N_EDGESC) return;
  int src = ei[e], dstv = ei[N_EDGESC + e], r = et[e];
  int pos = rowptr[dstv] + atomicAdd(&cursor[dstv], 1);
  ep[pos] = src | (r << 16);
  einvc[pos] = 1.0f / fmaxf(cnt[(size_t)r*N_NODESC + dstv], 1.0f);
}

// graph boundaries from sorted batch: grow[g] = first node of graph g, grow[NUM_M] = N
__global__ __launch_bounds__(256) void k_bnd(const int* __restrict__ batch, int* __restrict__ grow){
  int i = blockIdx.x*256 + threadIdx.x;
  if (i >= N_NODESC) return;
  int b = batch[i];
  if (i == 0){ for (int g = 0; g <= b; g++) grow[g] = 0; }
  else {
    int pb = batch[i-1];
    for (int g = pb+1; g <= b; g++) grow[g] = i;
  }
  if (i == N_NODESC-1){ for (int g = b+1; g <= NUM_MC; g++) grow[g] = N_NODESC; }
}

// weight transpose+convert: dst[mat][n][k] = bf16(src[mat][k][n])
__global__ __launch_bounds__(256) void k_wt(const float* __restrict__ src, ushort* __restrict__ dst,
                                            int K, int N, int total){
  int idx = blockIdx.x*256 + threadIdx.x;
  if (idx >= total) return;
  int kn = K*N;
  int mat = idx / kn, rem = idx - mat*kn;
  int k = rem / N, n = rem - k*N;
  dst[(size_t)mat*kn + (size_t)n*K + k] = f2bf(src[idx]);
}

__global__ __launch_bounds__(256) void k_cvt4(const float4* __restrict__ src, ushort4* __restrict__ dst,
                                              int n4, int relu){
  int i = blockIdx.x*256 + threadIdx.x;
  if (i >= n4) return;
  float4 v = src[i];
  if (relu){ v.x=fmaxf(v.x,0.f); v.y=fmaxf(v.y,0.f); v.z=fmaxf(v.z,0.f); v.w=fmaxf(v.w,0.f); }
  ushort4 o; o.x=f2bf(v.x); o.y=f2bf(v.y); o.z=f2bf(v.z); o.w=f2bf(v.w);
  dst[i] = o;
}

// one wave per dst: sum hrel[rel][src]/cnt over CSR in-edges, add nxt (Wroot out).
// if curbOut: write bf16 relu(result) ONLY; else write fp32 result to nxt.
__global__ __launch_bounds__(256) void k_gather(const ushort* __restrict__ hrel, float* __restrict__ nxt,
                                                ushort* __restrict__ curbOut,
                                                const int* __restrict__ rowptr, const int* __restrict__ ep,
                                                const float* __restrict__ einvc){
  int dstv = blockIdx.x*4 + (threadIdx.x >> 6);
  if (dstv >= N_NODESC) return;
  int lane = threadIdx.x & 63;
  int beg = rowptr[dstv], end = rowptr[dstv+1];
  float ax=0.f, ay=0.f, az=0.f, aw=0.f;
  for (int p = beg; p < end; p++){
    int pk = ep[p];
    float ic = einvc[p];
    int src = pk & 0xffff, r = pk >> 16;
    const ushort4 h = *(const ushort4*)(hrel + ((size_t)r*N_NODESC + src)*DC + lane*4);
    ax = fmaf(bf2f(h.x), ic, ax);
    ay = fmaf(bf2f(h.y), ic, ay);
    az = fmaf(bf2f(h.z), ic, az);
    aw = fmaf(bf2f(h.w), ic, aw);
  }
  float* np_ = nxt + (size_t)dstv*DC + lane*4;
  float4 v = *(const float4*)np_;
  v.x += ax; v.y += ay; v.z += az; v.w += aw;
  if (curbOut){
    ushort4 o;
    o.x = f2bf(fmaxf(v.x,0.f)); o.y = f2bf(fmaxf(v.y,0.f));
    o.z = f2bf(fmaxf(v.z,0.f)); o.w = f2bf(fmaxf(v.w,0.f));
    *(ushort4*)(curbOut + (size_t)dstv*DC + lane*4) = o;
  } else {
    *(float4*)np_ = v;
  }
}

// pooling: rows 0..63 = relu(H_R); rows 64..1087 = relu(mean of feats over graph segment)
__global__ __launch_bounds__(256) void k_pool(const float* __restrict__ feats, const int* __restrict__ grow,
                                              const float* __restrict__ H_R, float* __restrict__ Hrelu){
  int row = blockIdx.x*4 + (threadIdx.x >> 6);
  if (row >= NUM_RC + NUM_MC) return;
  int lane = threadIdx.x & 63;
  float4 v;
  if (row < NUM_RC){
    v = *(const float4*)(H_R + (size_t)row*DC + lane*4);
  } else {
    int g = row - NUM_RC;
    int beg = grow[g], end = grow[g+1];
    float ax=0.f, ay=0.f, az=0.f, aw=0.f;
    for (int i = beg; i < end; i++){
      const float4 f = *(const float4*)(feats + (size_t)i*DC + lane*4);
      ax += f.x; ay += f.y; az += f.z; aw += f.w;
    }
    float ic = 1.0f / fmaxf((float)(end-beg), 1.0f);
    v.x = ax*ic; v.y = ay*ic; v.z = az*ic; v.w = aw*ic;
  }
  v.x = fmaxf(v.x,0.f); v.y = fmaxf(v.y,0.f); v.z = fmaxf(v.z,0.f); v.w = fmaxf(v.w,0.f);
  *(float4*)(Hrelu + (size_t)row*DC + lane*4) = v;
}

// ---------------- bf16 MFMA GEMM: C = A[M,K] @ Bt[N,K]^T (+bias) ------------
__global__ __launch_bounds__(256) void k_gemm_bf16(
    const ushort* __restrict__ A, int lda,
    const ushort* __restrict__ Bt0, int ldb,
    void* __restrict__ Cout0, int ldc,
    int M, int N, int K,
    const float* __restrict__ bias, int flags,
    size_t strideB, size_t strideC)
{
  __shared__ ushort As[128*32];
  __shared__ ushort Bs[128*32];
  const int tid = threadIdx.x;
  const int wave = tid >> 6, lane = tid & 63;
  const int m0 = blockIdx.y * 128, n0 = blockIdx.x * 128;
  const ushort* Bt = Bt0 + blockIdx.z * strideB;
  const int wm = (wave >> 1) * 64, wn = (wave & 1) * 64;
  const int qa = lane >> 4, lm = lane & 15;

  const int srow = wave*32 + (lane >> 2);
  const int scol = (lane & 3) * 8;

  floatx4 acc[4][4] = {};

  for (int k0 = 0; k0 < K; k0 += 32){
    {
      int r1 = m0 + srow;      if (r1 > M-1) r1 = M-1;
      int r2 = m0 + srow + 16; if (r2 > M-1) r2 = M-1;
      gld16(A + (size_t)r1*lda + k0 + scol, (char*)As + (size_t)srow*64 + (lane&3)*16);
      gld16(A + (size_t)r2*lda + k0 + scol, (char*)As + (size_t)(srow+16)*64 + (lane&3)*16);
      gld16(Bt + (size_t)(n0 + srow)*ldb + k0 + scol,      (char*)Bs + (size_t)srow*64 + (lane&3)*16);
      gld16(Bt + (size_t)(n0 + srow + 16)*ldb + k0 + scol, (char*)Bs + (size_t)(srow+16)*64 + (lane&3)*16);
    }
    __syncthreads();
    short8 af[4], bfv[4];
    #pragma unroll
    for (int mt = 0; mt < 4; mt++)
      af[mt] = *(const short8*)(As + (size_t)(wm + mt*16 + lm)*32 + qa*8);
    #pragma unroll
    for (int nt = 0; nt < 4; nt++)
      bfv[nt] = *(const short8*)(Bs + (size_t)(wn + nt*16 + lm)*32 + qa*8);
    #pragma unroll
    for (int mt = 0; mt < 4; mt++)
      #pragma unroll
      for (int nt = 0; nt < 4; nt++)
        acc[mt][nt] = __builtin_amdgcn_mfma_f32_16x16x32_bf16(af[mt], bfv[nt], acc[mt][nt], 0, 0, 0);
    __syncthreads();
  }

  char* Cout = (char*)Cout0;
  #pragma unroll
  for (int mt = 0; mt < 4; mt++){
    #pragma unroll
    for (int i = 0; i < 4; i++){
      int row = m0 + wm + mt*16 + qa*4 + i;
      if (row >= M) continue;
      #pragma unroll
      for (int nt = 0; nt < 4; nt++){
        int col = n0 + wn + nt*16 + lm;
        float v = acc[mt][nt][i];
        if (flags & 2) v += bias[col];
        if (flags & 1)
          ((ushort*)Cout)[blockIdx.z*strideC + (size_t)row*ldc + col] = f2bf(v);
        else
          ((float*)Cout)[blockIdx.z*strideC + (size_t)row*ldc + col] = v;
      }
    }
  }
}

// ---------------- fp32 GEMM (small matrices) ----------------
__global__ __launch_bounds__(256) void k_gemm(
    const float* __restrict__ A, int lda,
    const float* __restrict__ B, int ldb,
    float* __restrict__ C, int ldc,
    int M, int N, int K,
    const float* __restrict__ bias, int flags)
{
  __shared__ __align__(16) float Asm[64][36];
  __shared__ __align__(16) float Bsm[32][64];
  const int tid = threadIdx.x;
  const int tx = tid & 15, ty = tid >> 4;
  const int m0 = blockIdx.y * 64, n0 = blockIdx.x * 64;
  const int am = tid >> 2, ak = (tid & 3) * 8;
  const int bk = tid >> 3, bn = (tid & 7) * 8;
  float acc[4][4] = {};
  for (int k0 = 0; k0 < K; k0 += 32){
    float4 a0, a1;
    int arow = m0 + am;
    if (arow < M){
      const float* ap = A + (size_t)arow*lda + (k0 + ak);
      a0 = *(const float4*)ap;
      a1 = *(const float4*)(ap + 4);
    } else {
      a0 = make_float4(0,0,0,0); a1 = a0;
    }
    const float* bp = B + (size_t)(k0 + bk)*ldb + (n0 + bn);
    float4 b0v = *(const float4*)bp;
    float4 b1v = *(const float4*)(bp + 4);
    *(float4*)&Asm[am][ak]   = a0;
    *(float4*)&Asm[am][ak+4] = a1;
    *(float4*)&Bsm[bk][bn]   = b0v;
    *(float4*)&Bsm[bk][bn+4] = b1v;
    __syncthreads();
    #pragma unroll
    for (int kk = 0; kk < 32; ++kk){
      float av[4], bv[4];
      #pragma unroll
      for (int i=0;i<4;i++) av[i] = Asm[ty*4+i][kk];
      #pragma unroll
      for (int j=0;j<4;j++) bv[j] = Bsm[kk][tx*4+j];
      #pragma unroll
      for (int i=0;i<4;i++)
        #pragma unroll
        for (int j=0;j<4;j++)
          acc[i][j] = fmaf(av[i], bv[j], acc[i][j]);
    }
    __syncthreads();
  }
  #pragma unroll
  for (int i=0;i<4;i++){
    int row = m0 + ty*4 + i;
    if (row >= M) continue;
    #pragma unroll
    for (int j=0;j<4;j++){
      int col = n0 + tx*4 + j;
      float v = acc[i][j];
      if (flags & 2) v += bias[col];
      if (flags & 1) v += C[(size_t)row*ldc + col];
      if (flags & 4) v = fmaxf(v, 0.0f);
      C[(size_t)row*ldc + col] = v;
    }
  }
}

// ---------------- sampling & head kernels ----------------
__global__ __launch_bounds__(256) void k_sample(const float* __restrict__ par, float* __restrict__ out,
                                                int row0, int half, uint32_t k0, uint32_t k1){
  int j = blockIdx.x*256 + threadIdx.x;
  if (j >= half) return;
  uint32_t o0, o1;
  tf2x32(k0, k1, (uint32_t)j, (uint32_t)(j + half), &o0, &o1);
  {
    int row = row0 + (j >> 8), col = j & 255;
    out[j] = par[(size_t)row*512 + col] + expf(par[(size_t)row*512 + 256 + col]) * bits_to_normal(o0);
  }
  {
    int i = j + half;
    int row = row0 + (i >> 8), col = i & 255;
    out[i] = par[(size_t)row*512 + col] + expf(par[(size_t)row*512 + 256 + col]) * bits_to_normal(o1);
  }
}

__global__ __launch_bounds__(64) void k_d2(const float* __restrict__ u, float* __restrict__ d2){
  int m = blockIdx.x, r = threadIdx.x;
  const float* um = u + (size_t)(NUM_RC + m)*DC;
  const float* ur = u + (size_t)r*DC;
  float s = 0.f;
  for (int d = 0; d < DC; ++d){ float df = um[d]-ur[d]; s = fmaf(df, df, s); }
  d2[m*NUM_RC + r] = s;
}

__device__ __forceinline__ void A_elem(float* An, const float* d2, int i, uint32_t bits, float inv_s){
  float logp = -0.5f * d2[i] * inv_s;
  float la = logp - logf(fmaxf(-expm1f(logp), 1e-20f));
  float f = bits_to_unit(bits);
  const float mn = 1e-6f, mx = 0.999999f;
  float U = fmaxf(f*(mx-mn) + mn, mn);
  float g = (la + logf(U) - log1pf(-U)) / 0.3f;
  An[i] = 1.0f / (1.0f + expf(-g));
}

__global__ __launch_bounds__(256) void k_A(const float* __restrict__ d2, const float* __restrict__ pg,
                                           float* __restrict__ An, uint32_t k0, uint32_t k1){
  const int HALF = (NUM_MC*NUM_RC)/2;
  int j = blockIdx.x*256 + threadIdx.x;
  if (j >= HALF) return;
  uint32_t o0, o1;
  tf2x32(k0, k1, (uint32_t)j, (uint32_t)(j + HALF), &o0, &o1);
  float inv_s = expf(-pg[0]);
  A_elem(An, d2, j, o0, inv_s);
  A_elem(An, d2, j + HALF, o1, inv_s);
}

__global__ __launch_bounds__(64) void k_rownorm(float* __restrict__ An){
  int m = blockIdx.x, r = threadIdx.x;
  float v = An[m*NUM_RC + r];
  float s = waveReduce(v);
  An[m*NUM_RC + r] = v / (s + 1e-8f);
}

__global__ __launch_bounds__(256) void k_logpqz(const float* __restrict__ zM, const float* __restrict__ pzm,
                                                const float* __restrict__ pzl, const float* __restrict__ qz,
                                                float* __restrict__ scal){
  int idx = blockIdx.x*256 + threadIdx.x;
  int m = idx >> 8, d = idx & 255;
  float z = zM[idx];
  float pm = pzm[idx], pl = pzl[idx];
  const float* qrow = qz + (size_t)(NUM_RC + m)*512;
  float qm = qrow[d], ql = qrow[256 + d];
  float tp = (z - pm) * expf(-pl);
  float tq = (z - qm) * expf(-ql);
  float term = (-pl - 0.5f*tp*tp) - (-ql - 0.5f*tq*tq);
  float s = waveReduce(term);
  if ((threadIdx.x & 63) == 0) atomicAdd(&scal[0], s);
}

__global__ __launch_bounds__(256) void k_out_head(const float* __restrict__ hid, const float* __restrict__ W2,
                                                  const float* __restrict__ b2, const int* __restrict__ y,
                                                  float* __restrict__ target, int M){
  int wave = threadIdx.x >> 6, lane = threadIdx.x & 63;
  int row = blockIdx.x*4 + wave;
  if (row >= M) return;
  const float* h = hid + (size_t)row*256;
  float p0 = 0.f, p1 = 0.f;
  #pragma unroll
  for (int c = 0; c < 4; c++){
    int d = lane*4 + c;
    float hv = h[d];
    p0 = fmaf(hv, W2[d*2+0], p0);
    p1 = fmaf(hv, W2[d*2+1], p1);
  }
  p0 = waveReduce(p0);
  p1 = waveReduce(p1);
  if (lane == 0){
    float l0 = p0 + b2[0], l1 = p1 + b2[1];
    float mx = fmaxf(l0, l1);
    float lse = mx + logf(expf(l0-mx) + expf(l1-mx));
    float lp = ((y[row] == 0) ? l0 : l1) - lse;
    atomicAdd(target, lp);
  }
}

__global__ __launch_bounds__(256) void k_reg(const float* __restrict__ d2, const int* __restrict__ yM,
                                             float* __restrict__ scal){
  int t = blockIdx.x*256 + threadIdx.x;
  float v = 0.f;
  if (t < 32*1024){
    int i = t >> 10, m = t & 1023;
    int col = i + (1 - yM[m]) * 32;
    v = sqrtf(fmaxf(d2[m*NUM_RC + col], 1e-12f));
  }
  float s = waveReduce(v);
  if ((threadIdx.x & 63) == 0) atomicAdd(&scal[3], s);
}

__global__ void k_final(const float* __restrict__ scal, float* __restrict__ out){
  float pred = -(scal[1] + 0.1f*scal[0]) / 1024.0f;
  float rat  = -scal[2] / 64.0f;
  float regm = scal[3] / 32768.0f;
  out[0] = pred + rat - 0.1f*regm;
}

// ---------------- launch ----------------
extern "C" void kernel_launch(void* const* d_in, const int* in_sizes, int n_in,
                              void* d_out, int out_size, void* d_ws, size_t ws_size,
                              hipStream_t stream) {
  const float* x         = (const float*)d_in[0];
  const int*   edge_index= (const int*)  d_in[1];
  const int*   edge_type = (const int*)  d_in[2];
  const int*   batch     = (const int*)  d_in[3];
  const int*   yM        = (const int*)  d_in[4];
  const int*   yR        = (const int*)  d_in[5];
  const float* H_R       = (const float*)d_in[6];
  const float* node_W    = (const float*)d_in[7];
  const float* node_b    = (const float*)d_in[8];
  const float* gcn_Wr    = (const float*)d_in[9];
  const float* gcn_Wroot = (const float*)d_in[10];
  const float* gcn_b     = (const float*)d_in[11];
  const float* pg_ls     = (const float*)d_in[12];
  const float* pu_W      = (const float*)d_in[13];
  const float* pu_b      = (const float*)d_in[14];
  const float* qz_W      = (const float*)d_in[15];
  const float* qz_b      = (const float*)d_in[16];
  const float* out_W1    = (const float*)d_in[17];
  const float* out_b1    = (const float*)d_in[18];
  const float* out_W2    = (const float*)d_in[19];
  const float* out_b2    = (const float*)d_in[20];
  float* out = (float*)d_out;

  char* base = (char*)d_ws;
  size_t off = 0;
  auto ALLOC = [&](size_t nbytes)->void*{
    void* p = base + off; off += (nbytes + 255) & ~(size_t)255; return p;
  };
  float*  nxt      = (float*) ALLOC((size_t)N_NODESC*DC*4);
  ushort* curb     = (ushort*)ALLOC((size_t)N_NODESC*DC*2);
  ushort* hrel     = (ushort*)ALLOC((size_t)N_RELC*N_NODESC*DC*2);
  ushort* xb       = (ushort*)ALLOC((size_t)N_NODESC*D_INC*2);
  ushort* node_Wt  = (ushort*)ALLOC((size_t)DC*D_INC*2);
  ushort* Wroot_t  = (ushort*)ALLOC((size_t)N_LAYERSC*DC*DC*2);
  ushort* Wr_t     = (ushort*)ALLOC((size_t)N_LAYERSC*N_RELC*DC*DC*2);
  float*  cnt      = (float*) ALLOC((size_t)N_RELC*N_NODESC*4);
  int*    deg      = (int*)   ALLOC((size_t)N_NODESC*4);
  int*    cursor   = (int*)   ALLOC((size_t)N_NODESC*4);
  int*    rowptr   = (int*)   ALLOC((size_t)(N_NODESC+1)*4);
  int*    ep       = (int*)   ALLOC((size_t)N_EDGESC*4);
  float*  einvc    = (float*) ALLOC((size_t)N_EDGESC*4);
  int*    grow     = (int*)   ALLOC((size_t)(NUM_MC+1)*4);
  float*  Hrelu    = (float*) ALLOC((size_t)1088*DC*4);
  float*  pu       = (float*) ALLOC((size_t)1088*512*4);
  float*  qz       = (float*) ALLOC((size_t)1088*512*4);
  float*  u        = (float*) ALLOC((size_t)1088*DC*4);
  float*  d2      = (float*)  ALLOC((size_t)NUM_MC*NUM_RC*4);
  float*  An      = (float*)  ALLOC((size_t)NUM_MC*NUM_RC*4);
  float*  pzm     = (float*)  ALLOC((size_t)NUM_MC*DC*4);
  float*  pzl     = (float*)  ALLOC((size_t)NUM_MC*DC*4);
  float*  zM      = (float*)  ALLOC((size_t)NUM_MC*DC*4);
  float*  zR      = (float*)  ALLOC((size_t)NUM_RC*DC*4);
  float*  hidM    = (float*)  ALLOC((size_t)NUM_MC*256*4);
  float*  hidR    = (float*)  ALLOC((size_t)NUM_RC*256*4);
  float*  scal    = (float*)  ALLOC(64);
  (void)ws_size; (void)in_sizes; (void)n_in; (void)out_size;

  uint32_t ya0,ya1,yb0,yb1,yc0,yc1,yd0,yd1;
  tf2x32(0u,42u, 0u,4u, &ya0,&ya1);
  tf2x32(0u,42u, 1u,5u, &yb0,&yb1);
  tf2x32(0u,42u, 2u,6u, &yc0,&yc1);
  tf2x32(0u,42u, 3u,7u, &yd0,&yd1);
  const uint32_t ku0=ya0,  ku1=yb0;
  const uint32_t ka0=yc0,  ka1=yd0;
  const uint32_t kzm0=ya1, kzm1=yb1;
  const uint32_t kzr0=yc1, kzr1=yd1;

  auto Z = [&](void* p, size_t n){
    int n4 = (int)(n/4);
    k_zero4<<<dim3((n4+255)/256), dim3(256), 0, stream>>>((float4*)p, n4);
  };
  auto GEMM = [&](const float* A, int lda, const float* B, int ldb, float* C, int ldc,
                  int M, int N, int K, const float* bias, int flags){
    k_gemm<<<dim3(N/64, (M+63)/64), dim3(256), 0, stream>>>(A, lda, B, ldb, C, ldc, M, N, K, bias, flags);
  };
  auto BGEMM = [&](const ushort* A, int lda, const ushort* Bt, int ldb, void* C, int ldc,
                   int M, int N, int K, const float* bias, int flags, int gz,
                   size_t strideB, size_t strideC){
    k_gemm_bf16<<<dim3(N/128, (M+127)/128, gz), dim3(256), 0, stream>>>(
        A, lda, Bt, ldb, C, ldc, M, N, K, bias, flags, strideB, strideC);
  };

  // ---- setup: histograms, CSR, graph boundaries ----
  Z(cnt, (size_t)N_RELC*N_NODESC);
  Z(deg, N_NODESC);
  Z(cursor, N_NODESC);
  Z(scal, 16);
  k_count<<<dim3((N_EDGESC+255)/256), dim3(256), 0, stream>>>(edge_index, edge_type, cnt, deg);
  k_scan <<<dim3(1), dim3(256), 0, stream>>>(deg, rowptr);
  k_fill2<<<dim3((N_EDGESC+255)/256), dim3(256), 0, stream>>>(edge_index, edge_type, cnt, rowptr, cursor, ep, einvc);
  k_bnd  <<<dim3((N_NODESC+255)/256), dim3(256), 0, stream>>>(batch, grow);

  // weight prep (transpose + bf16)
  {
    int t1 = D_INC*DC;
    k_wt<<<dim3((t1+255)/256), dim3(256), 0, stream>>>(node_W, node_Wt, D_INC, DC, t1);
    int t2 = N_LAYERSC*DC*DC;
    k_wt<<<dim3((t2+255)/256), dim3(256), 0, stream>>>(gcn_Wroot, Wroot_t, DC, DC, t2);
    int t3 = N_LAYERSC*N_RELC*DC*DC;
    k_wt<<<dim3((t3+255)/256), dim3(256), 0, stream>>>(gcn_Wr, Wr_t, DC, DC, t3);
    int n4 = (N_NODESC*D_INC)/4;
    k_cvt4<<<dim3((n4+255)/256), dim3(256), 0, stream>>>((const float4*)x, (ushort4*)xb, n4, 0);
  }

  // ---- input projection: curb = bf16(x @ node_W + node_b) ----
  BGEMM(xb, D_INC, node_Wt, D_INC, curb, DC, N_NODESC, DC, D_INC, node_b, 1|2, 1, 0, 0);

  // ---- RGCN layers (transform, then CSR gather) ----
  for (int l = 0; l < N_LAYERSC; l++){
    BGEMM(curb, DC, Wroot_t + (size_t)l*DC*DC, DC, nxt, DC, N_NODESC, DC, DC, gcn_b + l*DC, 2, 1, 0, 0);
    BGEMM(curb, DC, Wr_t + (size_t)l*N_RELC*DC*DC, DC, hrel, DC, N_NODESC, DC, DC, nullptr, 1, N_RELC,
          (size_t)DC*DC, (size_t)N_NODESC*DC);
    ushort* cOut = (l < N_LAYERSC-1) ? curb : nullptr;
    k_gather<<<dim3((N_NODESC+3)/4), dim3(256), 0, stream>>>(hrel, nxt, cOut, rowptr, ep, einvc);
  }
  // nxt == final feats (fp32, no relu)

  // ---- pool (sorted batch segments) + concat + relu ----
  k_pool<<<dim3((NUM_RC+NUM_MC+3)/4), dim3(256), 0, stream>>>(nxt, grow, H_R, Hrelu);

  // ---- pu / qz projections (fp32) ----
  GEMM(Hrelu, DC, pu_W, 512, pu, 512, 1088, 512, DC, pu_b, 2);
  GEMM(Hrelu, DC, qz_W, 512, qz, 512, 1088, 512, DC, qz_b, 2);

  // ---- u sampling ----
  k_sample<<<dim3(544), dim3(256), 0, stream>>>(pu, u, 0, (1088*DC)/2, ku0, ku1);

  // ---- d2, A, An ----
  k_d2<<<dim3(NUM_MC), dim3(64), 0, stream>>>(u, d2);
  k_A <<<dim3(128), dim3(256), 0, stream>>>(d2, pg_ls, An, ka0, ka1);
  k_rownorm<<<dim3(NUM_MC), dim3(64), 0, stream>>>(An);

  // ---- pz = An @ qz[:64] ----
  GEMM(An, NUM_RC, qz,        512, pzm, DC, NUM_MC, DC, NUM_RC, nullptr, 0);
  GEMM(An, NUM_RC, qz + 256,  512, pzl, DC, NUM_MC, DC, NUM_RC, nullptr, 0);

  // ---- z sampling + log_pqz ----
  k_sample<<<dim3(512), dim3(256), 0, stream>>>(qz, zM, NUM_RC, (NUM_MC*DC)/2, kzm0, kzm1);
  k_logpqz<<<dim3(1024), dim3(256), 0, stream>>>(zM, pzm, pzl, qz, scal);
  k_sample<<<dim3(32), dim3(256), 0, stream>>>(qz, zR, 0, (NUM_RC*DC)/2, kzr0, kzr1);

  // ---- output heads ----
  GEMM(zM, DC, out_W1,           256, hidM, 256, NUM_MC, 256, DC, out_b1, 2);
  GEMM(u + (size_t)NUM_RC*DC, DC, out_W1 + 256*256, 256, hidM, 256, NUM_MC, 256, DC, nullptr, 1|4);
  k_out_head<<<dim3(NUM_MC/4), dim3(256), 0, stream>>>(hidM, out_W2, out_b2, yM, scal+1, NUM_MC);

  GEMM(zR, DC, out_W1,           256, hidR, 256, NUM_RC, 256, DC, out_b1, 2);
  GEMM(u,  DC, out_W1 + 256*256, 256, hidR, 256, NUM_RC, 256, DC, nullptr, 1|4);
  k_out_head<<<dim3(NUM_RC/4), dim3(256), 0, stream>>>(hidR, out_W2, out_b2, yR, scal+2, NUM_RC);

  // ---- reg term & final combine ----
  k_reg<<<dim3(128), dim3(256), 0, stream>>>(d2, yM, scal);
  k_final<<<dim3(1), dim3(1), 0, stream>>>(scal, out);
}

// Round 4
// 877.544 us; speedup vs baseline: 8.7395x; 1.2396x over previous
//
#include <hip/hip_runtime.h>
#include <stdint.h>

#define N_NODESC 50000
#define N_EDGESC 200000
#define D_INC 128
#define DC 256
#define N_LAYERSC 4
#define N_RELC 4
#define NUM_MC 1024
#define NUM_RC 64
#define NBLK_SCAN ((N_NODESC + 255) / 256)   // 196

typedef __attribute__((ext_vector_type(4))) float floatx4;
typedef __attribute__((ext_vector_type(8))) short short8;

// ---------------- threefry2x32 (JAX-compatible) ----------------
__host__ __device__ __forceinline__ uint32_t rotl32(uint32_t x, int r){ return (x<<r)|(x>>(32-r)); }

__host__ __device__ inline void tf2x32(uint32_t k0, uint32_t k1, uint32_t x0, uint32_t x1,
                                       uint32_t* o0, uint32_t* o1){
  uint32_t k2 = k0 ^ k1 ^ 0x1BD11BDAu;
#define TFR(r) { x0 += x1; x1 = rotl32(x1, (r)); x1 ^= x0; }
  x0 += k0; x1 += k1;
  TFR(13) TFR(15) TFR(26) TFR(6)
  x0 += k1; x1 += k2 + 1u;
  TFR(17) TFR(29) TFR(16) TFR(24)
  x0 += k2; x1 += k0 + 2u;
  TFR(13) TFR(15) TFR(26) TFR(6)
  x0 += k0; x1 += k1 + 3u;
  TFR(17) TFR(29) TFR(16) TFR(24)
  x0 += k1; x1 += k2 + 4u;
  TFR(13) TFR(15) TFR(26) TFR(6)
  x0 += k2; x1 += k0 + 5u;
#undef TFR
  *o0 = x0; *o1 = x1;
}

__device__ __forceinline__ float erfinv_f32(float x){
  float w = -log1pf(-x*x);
  float p;
  if (w < 5.0f){
    w -= 2.5f;
    p = 2.81022636e-08f;
    p = fmaf(p, w, 3.43273939e-07f);
    p = fmaf(p, w, -3.5233877e-06f);
    p = fmaf(p, w, -4.39150654e-06f);
    p = fmaf(p, w, 0.00021858087f);
    p = fmaf(p, w, -0.00125372503f);
    p = fmaf(p, w, -0.00417768164f);
    p = fmaf(p, w, 0.246640727f);
    p = fmaf(p, w, 1.50140941f);
  } else {
    w = sqrtf(w) - 3.0f;
    p = -0.000200214257f;
    p = fmaf(p, w, 0.000100950558f);
    p = fmaf(p, w, 0.00134934322f);
    p = fmaf(p, w, -0.00367342844f);
    p = fmaf(p, w, 0.00573950773f);
    p = fmaf(p, w, -0.0076224613f);
    p = fmaf(p, w, 0.00943887047f);
    p = fmaf(p, w, 1.00167406f);
    p = fmaf(p, w, 2.83297682f);
  }
  return p*x;
}

__device__ __forceinline__ float bits_to_unit(uint32_t b){
  return __uint_as_float((b >> 9) | 0x3f800000u) - 1.0f;
}

__device__ __forceinline__ float bits_to_normal(uint32_t b){
  float f = bits_to_unit(b);
  const float lo = -0.99999994f;
  float u = f * (1.0f - lo) + lo;
  u = fmaxf(u, lo);
  return 1.41421356f * erfinv_f32(u);
}

__device__ __forceinline__ float waveReduce(float v){
  #pragma unroll
  for (int m = 1; m < 64; m <<= 1) v += __shfl_xor(v, m, 64);
  return v;
}

__device__ __forceinline__ ushort f2bf(float f){
  uint32_t u = __float_as_uint(f);
  uint32_t r = u + 0x7fffu + ((u>>16)&1u);
  return (ushort)(r>>16);
}
__device__ __forceinline__ float bf2f(ushort h){
  return __uint_as_float(((uint32_t)h)<<16);
}

typedef const __attribute__((address_space(1))) void* gas_t;
typedef __attribute__((address_space(3))) void* las_t;
__device__ __forceinline__ void gld16(const void* g, void* l){
  __builtin_amdgcn_global_load_lds((gas_t)g, (las_t)l, 16, 0, 0);
}

// ---------------- utility kernels ----------------
__global__ __launch_bounds__(256) void k_zero4(float4* p, int n4){
  int i = blockIdx.x*256 + threadIdx.x;
  if (i < n4) p[i] = make_float4(0.f,0.f,0.f,0.f);
}

__global__ __launch_bounds__(256) void k_count(const int* __restrict__ ei, const int* __restrict__ et,
                                               float* __restrict__ cnt, int* __restrict__ deg){
  int e = blockIdx.x*256 + threadIdx.x;
  if (e >= N_EDGESC) return;
  int r = et[e], dstv = ei[N_EDGESC + e];
  atomicAdd(&cnt[(size_t)r*N_NODESC + dstv], 1.0f);
  atomicAdd(&deg[dstv], 1);
}

// ---- parallel exclusive scan of deg -> rowptr (3 kernels) ----
__global__ __launch_bounds__(256) void k_scan1(const int* __restrict__ deg, int* __restrict__ bsum){
  int i = blockIdx.x*256 + threadIdx.x;
  int v = (i < N_NODESC) ? deg[i] : 0;
  #pragma unroll
  for (int m = 1; m < 64; m <<= 1) v += __shfl_xor(v, m, 64);
  __shared__ int ws_[4];
  if ((threadIdx.x & 63) == 0) ws_[threadIdx.x >> 6] = v;
  __syncthreads();
  if (threadIdx.x == 0) bsum[blockIdx.x] = ws_[0]+ws_[1]+ws_[2]+ws_[3];
}

__global__ __launch_bounds__(256) void k_scan2(int* __restrict__ bsum, int* __restrict__ boff){
  __shared__ int s[256];
  int t = threadIdx.x;
  s[t] = (t < NBLK_SCAN) ? bsum[t] : 0;
  __syncthreads();
  if (t == 0){
    int run = 0;
    for (int i = 0; i < NBLK_SCAN; i++){ int v = s[i]; s[i] = run; run += v; }
  }
  __syncthreads();
  if (t < NBLK_SCAN) boff[t] = s[t];
}

__global__ __launch_bounds__(256) void k_scan3(const int* __restrict__ deg, const int* __restrict__ boff,
                                               int* __restrict__ rowptr){
  int i = blockIdx.x*256 + threadIdx.x;
  int lane = threadIdx.x & 63, w = threadIdx.x >> 6;
  int d = (i < N_NODESC) ? deg[i] : 0;
  int v = d;
  #pragma unroll
  for (int off = 1; off < 64; off <<= 1){
    int t = __shfl_up(v, off, 64);
    if (lane >= off) v += t;
  }
  __shared__ int wt[4];
  if (lane == 63) wt[w] = v;
  __syncthreads();
  int wo = 0;
  for (int k = 0; k < w; k++) wo += wt[k];
  int ex = boff[blockIdx.x] + wo + v - d;
  if (i <= N_NODESC) rowptr[i] = ex;
}

// fill CSR: ep[pos] = src | (rel<<16); einvc[pos] = 1/max(cnt[r,dst],1)
__global__ __launch_bounds__(256) void k_fill2(const int* __restrict__ ei, const int* __restrict__ et,
                                               const float* __restrict__ cnt, const int* __restrict__ rowptr,
                                               int* __restrict__ cursor, int* __restrict__ ep,
                                               float* __restrict__ einvc){
  int e = blockIdx.x*256 + threadIdx.x;
  if (e >= N_EDGESC) return;
  int src = ei[e], dstv = ei[N_EDGESC + e], r = et[e];
  int pos = rowptr[dstv] + atomicAdd(&cursor[dstv], 1);
  ep[pos] = src | (r << 16);
  einvc[pos] = 1.0f / fmaxf(cnt[(size_t)r*N_NODESC + dstv], 1.0f);
}

__global__ __launch_bounds__(256) void k_bnd(const int* __restrict__ batch, int* __restrict__ grow){
  int i = blockIdx.x*256 + threadIdx.x;
  if (i >= N_NODESC) return;
  int b = batch[i];
  if (i == 0){ for (int g = 0; g <= b; g++) grow[g] = 0; }
  else {
    int pb = batch[i-1];
    for (int g = pb+1; g <= b; g++) grow[g] = i;
  }
  if (i == N_NODESC-1){ for (int g = b+1; g <= NUM_MC; g++) grow[g] = N_NODESC; }
}

// weight transpose+convert (node_W): dst[n][k] = bf16(src[k][n])
__global__ __launch_bounds__(256) void k_wt(const float* __restrict__ src, ushort* __restrict__ dst,
                                            int K, int N, int total){
  int idx = blockIdx.x*256 + threadIdx.x;
  if (idx >= total) return;
  int k = idx / N, n = idx - k*N;
  dst[(size_t)n*K + k] = f2bf(src[idx]);
}

// concatenated per-layer weights: Wcat[l][n(1280)][k(256)];
// n<256 -> Wroot[l][k][n]; else r=(n-256)>>8 -> Wr[l][r][k][(n-256)&255]
__global__ __launch_bounds__(256) void k_wcat(const float* __restrict__ Wroot, const float* __restrict__ Wr,
                                              ushort* __restrict__ Wcat){
  int idx = blockIdx.x*256 + threadIdx.x;
  if (idx >= N_LAYERSC*1280*DC) return;
  int l = idx / (1280*DC), rem = idx - l*(1280*DC);
  int n = rem / DC, k = rem - n*DC;
  float v;
  if (n < DC) v = Wroot[((size_t)l*DC + k)*DC + n];
  else {
    int r = (n - DC) >> 8, nn = (n - DC) & 255;
    v = Wr[(((size_t)l*N_RELC + r)*DC + k)*DC + nn];
  }
  Wcat[idx] = f2bf(v);
}

__global__ __launch_bounds__(256) void k_cvt4(const float4* __restrict__ src, ushort4* __restrict__ dst,
                                              int n4){
  int i = blockIdx.x*256 + threadIdx.x;
  if (i >= n4) return;
  float4 v = src[i];
  ushort4 o; o.x=f2bf(v.x); o.y=f2bf(v.y); o.z=f2bf(v.z); o.w=f2bf(v.w);
  dst[i] = o;
}

// one wave per dst: out = slab0[dst] + gcn_b + sum_edges slab[1+r][src]*invc ; write bf16 (relu if flag)
__global__ __launch_bounds__(256) void k_gather(const ushort* __restrict__ slabs, const float* __restrict__ bias,
                                                ushort* __restrict__ curbOut, int relu,
                                                const int* __restrict__ rowptr, const int* __restrict__ ep,
                                                const float* __restrict__ einvc){
  int dstv = blockIdx.x*4 + (threadIdx.x >> 6);
  if (dstv >= N_NODESC) return;
  int lane = threadIdx.x & 63;
  int beg = rowptr[dstv], end = rowptr[dstv+1];
  const ushort4 w0 = *(const ushort4*)(slabs + (size_t)dstv*DC + lane*4);
  const float4 bv = *(const float4*)(bias + lane*4);
  float ax = bf2f(w0.x) + bv.x, ay = bf2f(w0.y) + bv.y;
  float az = bf2f(w0.z) + bv.z, aw = bf2f(w0.w) + bv.w;
  for (int p = beg; p < end; p++){
    int pk = ep[p];
    float ic = einvc[p];
    int src = pk & 0xffff, r = pk >> 16;
    const ushort4 h = *(const ushort4*)(slabs + ((size_t)(1+r)*N_NODESC + src)*DC + lane*4);
    ax = fmaf(bf2f(h.x), ic, ax);
    ay = fmaf(bf2f(h.y), ic, ay);
    az = fmaf(bf2f(h.z), ic, az);
    aw = fmaf(bf2f(h.w), ic, aw);
  }
  if (relu){ ax=fmaxf(ax,0.f); ay=fmaxf(ay,0.f); az=fmaxf(az,0.f); aw=fmaxf(aw,0.f); }
  ushort4 o; o.x=f2bf(ax); o.y=f2bf(ay); o.z=f2bf(az); o.w=f2bf(aw);
  *(ushort4*)(curbOut + (size_t)dstv*DC + lane*4) = o;
}

// pooling from bf16 feats: rows 0..63 = relu(H_R); rows 64.. = relu(segment mean)
__global__ __launch_bounds__(256) void k_pool(const ushort* __restrict__ featsb, const int* __restrict__ grow,
                                              const float* __restrict__ H_R, float* __restrict__ Hrelu){
  int row = blockIdx.x*4 + (threadIdx.x >> 6);
  if (row >= NUM_RC + NUM_MC) return;
  int lane = threadIdx.x & 63;
  float4 v;
  if (row < NUM_RC){
    v = *(const float4*)(H_R + (size_t)row*DC + lane*4);
  } else {
    int g = row - NUM_RC;
    int beg = grow[g], end = grow[g+1];
    float ax=0.f, ay=0.f, az=0.f, aw=0.f;
    for (int i = beg; i < end; i++){
      const ushort4 f = *(const ushort4*)(featsb + (size_t)i*DC + lane*4);
      ax += bf2f(f.x); ay += bf2f(f.y); az += bf2f(f.z); aw += bf2f(f.w);
    }
    float ic = 1.0f / fmaxf((float)(end-beg), 1.0f);
    v.x = ax*ic; v.y = ay*ic; v.z = az*ic; v.w = aw*ic;
  }
  v.x = fmaxf(v.x,0.f); v.y = fmaxf(v.y,0.f); v.z = fmaxf(v.z,0.f); v.w = fmaxf(v.w,0.f);
  *(float4*)(Hrelu + (size_t)row*DC + lane*4) = v;
}

// ---------------- bf16 MFMA GEMM: C = A[M,K] @ Bt[N,K]^T (+bias) ------------
// flags: 1 = output bf16, 2 = add bias, 8 = slabbed bf16 output (strideC = slab stride)
__global__ __launch_bounds__(256) void k_gemm_bf16(
    const ushort* __restrict__ A, int lda,
    const ushort* __restrict__ Bt0, int ldb,
    void* __restrict__ Cout0, int ldc,
    int M, int N, int K,
    const float* __restrict__ bias, int flags,
    size_t strideB, size_t strideC)
{
  __shared__ ushort As[128*32];
  __shared__ ushort Bs[128*32];
  const int tid = threadIdx.x;
  const int wave = tid >> 6, lane = tid & 63;
  const int m0 = blockIdx.y * 128, n0 = blockIdx.x * 128;
  const ushort* Bt = Bt0 + blockIdx.z * strideB;
  const int wm = (wave >> 1) * 64, wn = (wave & 1) * 64;
  const int qa = lane >> 4, lm = lane & 15;

  const int srow = wave*32 + (lane >> 2);
  const int scol = (lane & 3) * 8;

  floatx4 acc[4][4] = {};

  for (int k0 = 0; k0 < K; k0 += 32){
    {
      int r1 = m0 + srow;      if (r1 > M-1) r1 = M-1;
      int r2 = m0 + srow + 16; if (r2 > M-1) r2 = M-1;
      gld16(A + (size_t)r1*lda + k0 + scol, (char*)As + (size_t)srow*64 + (lane&3)*16);
      gld16(A + (size_t)r2*lda + k0 + scol, (char*)As + (size_t)(srow+16)*64 + (lane&3)*16);
      gld16(Bt + (size_t)(n0 + srow)*ldb + k0 + scol,      (char*)Bs + (size_t)srow*64 + (lane&3)*16);
      gld16(Bt + (size_t)(n0 + srow + 16)*ldb + k0 + scol, (char*)Bs + (size_t)(srow+16)*64 + (lane&3)*16);
    }
    __syncthreads();
    short8 af[4], bfv[4];
    #pragma unroll
    for (int mt = 0; mt < 4; mt++)
      af[mt] = *(const short8*)(As + (size_t)(wm + mt*16 + lm)*32 + qa*8);
    #pragma unroll
    for (int nt = 0; nt < 4; nt++)
      bfv[nt] = *(const short8*)(Bs + (size_t)(wn + nt*16 + lm)*32 + qa*8);
    #pragma unroll
    for (int mt = 0; mt < 4; mt++)
      #pragma unroll
      for (int nt = 0; nt < 4; nt++)
        acc[mt][nt] = __builtin_amdgcn_mfma_f32_16x16x32_bf16(af[mt], bfv[nt], acc[mt][nt], 0, 0, 0);
    __syncthreads();
  }

  char* Cout = (char*)Cout0;
  #pragma unroll
  for (int mt = 0; mt < 4; mt++){
    #pragma unroll
    for (int i = 0; i < 4; i++){
      int row = m0 + wm + mt*16 + qa*4 + i;
      if (row >= M) continue;
      #pragma unroll
      for (int nt = 0; nt < 4; nt++){
        int col = n0 + wn + nt*16 + lm;
        float v = acc[mt][nt][i];
        if (flags & 2) v += bias[col];
        if (flags & 8)
          ((ushort*)Cout)[(size_t)(col>>8)*strideC + (size_t)row*256 + (col&255)] = f2bf(v);
        else if (flags & 1)
          ((ushort*)Cout)[blockIdx.z*strideC + (size_t)row*ldc + col] = f2bf(v);
        else
          ((float*)Cout)[blockIdx.z*strideC + (size_t)row*ldc + col] = v;
      }
    }
  }
}

// ---------------- fp32 GEMM (small matrices) ----------------
__global__ __launch_bounds__(256) void k_gemm(
    const float* __restrict__ A, int lda,
    const float* __restrict__ B, int ldb,
    float* __restrict__ C, int ldc,
    int M, int N, int K,
    const float* __restrict__ bias, int flags)
{
  __shared__ __align__(16) float Asm[64][36];
  __shared__ __align__(16) float Bsm[32][64];
  const int tid = threadIdx.x;
  const int tx = tid & 15, ty = tid >> 4;
  const int m0 = blockIdx.y * 64, n0 = blockIdx.x * 64;
  const int am = tid >> 2, ak = (tid & 3) * 8;
  const int bk = tid >> 3, bn = (tid & 7) * 8;
  float acc[4][4] = {};
  for (int k0 = 0; k0 < K; k0 += 32){
    float4 a0, a1;
    int arow = m0 + am;
    if (arow < M){
      const float* ap = A + (size_t)arow*lda + (k0 + ak);
      a0 = *(const float4*)ap;
      a1 = *(const float4*)(ap + 4);
    } else {
      a0 = make_float4(0,0,0,0); a1 = a0;
    }
    const float* bp = B + (size_t)(k0 + bk)*ldb + (n0 + bn);
    float4 b0v = *(const float4*)bp;
    float4 b1v = *(const float4*)(bp + 4);
    *(float4*)&Asm[am][ak]   = a0;
    *(float4*)&Asm[am][ak+4] = a1;
    *(float4*)&Bsm[bk][bn]   = b0v;
    *(float4*)&Bsm[bk][bn+4] = b1v;
    __syncthreads();
    #pragma unroll
    for (int kk = 0; kk < 32; ++kk){
      float av[4], bv[4];
      #pragma unroll
      for (int i=0;i<4;i++) av[i] = Asm[ty*4+i][kk];
      #pragma unroll
      for (int j=0;j<4;j++) bv[j] = Bsm[kk][tx*4+j];
      #pragma unroll
      for (int i=0;i<4;i++)
        #pragma unroll
        for (int j=0;j<4;j++)
          acc[i][j] = fmaf(av[i], bv[j], acc[i][j]);
    }
    __syncthreads();
  }
  #pragma unroll
  for (int i=0;i<4;i++){
    int row = m0 + ty*4 + i;
    if (row >= M) continue;
    #pragma unroll
    for (int j=0;j<4;j++){
      int col = n0 + tx*4 + j;
      float v = acc[i][j];
      if (flags & 2) v += bias[col];
      if (flags & 1) v += C[(size_t)row*ldc + col];
      if (flags & 4) v = fmaxf(v, 0.0f);
      C[(size_t)row*ldc + col] = v;
    }
  }
}

// ---------------- sampling & head kernels ----------------
// u for all 1088 rows; also scatter into repR (rows<64, cols 256..511) / repM (rows>=64)
__global__ __launch_bounds__(256) void k_sample_u(const float* __restrict__ pu, float* __restrict__ u,
                                                  float* __restrict__ repR, float* __restrict__ repM,
                                                  uint32_t k0, uint32_t k1){
  const int half = (1088*DC)/2;
  int j = blockIdx.x*256 + threadIdx.x;
  if (j >= half) return;
  uint32_t o0, o1;
  tf2x32(k0, k1, (uint32_t)j, (uint32_t)(j + half), &o0, &o1);
  #pragma unroll
  for (int t = 0; t < 2; t++){
    int i = j + t*half;
    uint32_t bits = t ? o1 : o0;
    int row = i >> 8, col = i & 255;
    float val = pu[(size_t)row*512 + col] + expf(pu[(size_t)row*512 + 256 + col]) * bits_to_normal(bits);
    u[i] = val;
    if (row < NUM_RC) repR[(size_t)row*512 + 256 + col] = val;
    else              repM[(size_t)(row - NUM_RC)*512 + 256 + col] = val;
  }
}

// zM: rows 64..1087 of qz -> repM cols 0..255
__global__ __launch_bounds__(256) void k_sample_zM(const float* __restrict__ qz, float* __restrict__ repM,
                                                   uint32_t k0, uint32_t k1){
  const int half = (NUM_MC*DC)/2;
  int j = blockIdx.x*256 + threadIdx.x;
  if (j >= half) return;
  uint32_t o0, o1;
  tf2x32(k0, k1, (uint32_t)j, (uint32_t)(j + half), &o0, &o1);
  #pragma unroll
  for (int t = 0; t < 2; t++){
    int i = j + t*half;
    uint32_t bits = t ? o1 : o0;
    int m = i >> 8, col = i & 255;
    int row = NUM_RC + m;
    float val = qz[(size_t)row*512 + col] + expf(qz[(size_t)row*512 + 256 + col]) * bits_to_normal(bits);
    repM[(size_t)m*512 + col] = val;
  }
}

// zR: rows 0..63 of qz -> repR cols 0..255
__global__ __launch_bounds__(256) void k_sample_zR(const float* __restrict__ qz, float* __restrict__ repR,
                                                   uint32_t k0, uint32_t k1){
  const int half = (NUM_RC*DC)/2;
  int j = blockIdx.x*256 + threadIdx.x;
  if (j >= half) return;
  uint32_t o0, o1;
  tf2x32(k0, k1, (uint32_t)j, (uint32_t)(j + half), &o0, &o1);
  #pragma unroll
  for (int t = 0; t < 2; t++){
    int i = j + t*half;
    uint32_t bits = t ? o1 : o0;
    int r = i >> 8, col = i & 255;
    float val = qz[(size_t)r*512 + col] + expf(qz[(size_t)r*512 + 256 + col]) * bits_to_normal(bits);
    repR[(size_t)r*512 + col] = val;
  }
}

__global__ __launch_bounds__(64) void k_d2(const float* __restrict__ u, float* __restrict__ d2){
  int m = blockIdx.x, r = threadIdx.x;
  const float* um = u + (size_t)(NUM_RC + m)*DC;
  const float* ur = u + (size_t)r*DC;
  float s = 0.f;
  for (int d = 0; d < DC; ++d){ float df = um[d]-ur[d]; s = fmaf(df, df, s); }
  d2[m*NUM_RC + r] = s;
}

__device__ __forceinline__ void A_elem(float* An, const float* d2, int i, uint32_t bits, float inv_s){
  float logp = -0.5f * d2[i] * inv_s;
  float la = logp - logf(fmaxf(-expm1f(logp), 1e-20f));
  float f = bits_to_unit(bits);
  const float mn = 1e-6f, mx = 0.999999f;
  float U = fmaxf(f*(mx-mn) + mn, mn);
  float g = (la + logf(U) - log1pf(-U)) / 0.3f;
  An[i] = 1.0f / (1.0f + expf(-g));
}

__global__ __launch_bounds__(256) void k_A(const float* __restrict__ d2, const float* __restrict__ pg,
                                           float* __restrict__ An, uint32_t k0, uint32_t k1){
  const int HALF = (NUM_MC*NUM_RC)/2;
  int j = blockIdx.x*256 + threadIdx.x;
  if (j >= HALF) return;
  uint32_t o0, o1;
  tf2x32(k0, k1, (uint32_t)j, (uint32_t)(j + HALF), &o0, &o1);
  float inv_s = expf(-pg[0]);
  A_elem(An, d2, j, o0, inv_s);
  A_elem(An, d2, j + HALF, o1, inv_s);
}

__global__ __launch_bounds__(64) void k_rownorm(float* __restrict__ An){
  int m = blockIdx.x, r = threadIdx.x;
  float v = An[m*NUM_RC + r];
  float s = waveReduce(v);
  An[m*NUM_RC + r] = v / (s + 1e-8f);
}

__global__ __launch_bounds__(256) void k_logpqz(const float* __restrict__ repM, const float* __restrict__ pzcat,
                                                const float* __restrict__ qz, float* __restrict__ scal){
  int idx = blockIdx.x*256 + threadIdx.x;
  int m = idx >> 8, d = idx & 255;
  float z  = repM[(size_t)m*512 + d];
  float pm = pzcat[(size_t)m*512 + d];
  float pl = pzcat[(size_t)m*512 + 256 + d];
  const float* qrow = qz + (size_t)(NUM_RC + m)*512;
  float qm = qrow[d], ql = qrow[256 + d];
  float tp = (z - pm) * expf(-pl);
  float tq = (z - qm) * expf(-ql);
  float term = (-pl - 0.5f*tp*tp) - (-ql - 0.5f*tq*tq);
  float s = waveReduce(term);
  if ((threadIdx.x & 63) == 0) atomicAdd(&scal[0], s);
}

__global__ __launch_bounds__(256) void k_out_head(const float* __restrict__ hid, const float* __restrict__ W2,
                                                  const float* __restrict__ b2, const int* __restrict__ y,
                                                  float* __restrict__ target, int M){
  int wave = threadIdx.x >> 6, lane = threadIdx.x & 63;
  int row = blockIdx.x*4 + wave;
  if (row >= M) return;
  const float* h = hid + (size_t)row*256;
  float p0 = 0.f, p1 = 0.f;
  #pragma unroll
  for (int c = 0; c < 4; c++){
    int d = lane*4 + c;
    float hv = h[d];
    p0 = fmaf(hv, W2[d*2+0], p0);
    p1 = fmaf(hv, W2[d*2+1], p1);
  }
  p0 = waveReduce(p0);
  p1 = waveReduce(p1);
  if (lane == 0){
    float l0 = p0 + b2[0], l1 = p1 + b2[1];
    float mx = fmaxf(l0, l1);
    float lse = mx + logf(expf(l0-mx) + expf(l1-mx));
    float lp = ((y[row] == 0) ? l0 : l1) - lse;
    atomicAdd(target, lp);
  }
}

__global__ __launch_bounds__(256) void k_reg(const float* __restrict__ d2, const int* __restrict__ yM,
                                             float* __restrict__ scal){
  int t = blockIdx.x*256 + threadIdx.x;
  float v = 0.f;
  if (t < 32*1024){
    int i = t >> 10, m = t & 1023;
    int col = i + (1 - yM[m]) * 32;
    v = sqrtf(fmaxf(d2[m*NUM_RC + col], 1e-12f));
  }
  float s = waveReduce(v);
  if ((threadIdx.x & 63) == 0) atomicAdd(&scal[3], s);
}

__global__ void k_final(const float* __restrict__ scal, float* __restrict__ out){
  float pred = -(scal[1] + 0.1f*scal[0]) / 1024.0f;
  float rat  = -scal[2] / 64.0f;
  float regm = scal[3] / 32768.0f;
  out[0] = pred + rat - 0.1f*regm;
}

// ---------------- launch ----------------
extern "C" void kernel_launch(void* const* d_in, const int* in_sizes, int n_in,
                              void* d_out, int out_size, void* d_ws, size_t ws_size,
                              hipStream_t stream) {
  const float* x         = (const float*)d_in[0];
  const int*   edge_index= (const int*)  d_in[1];
  const int*   edge_type = (const int*)  d_in[2];
  const int*   batch     = (const int*)  d_in[3];
  const int*   yM        = (const int*)  d_in[4];
  const int*   yR        = (const int*)  d_in[5];
  const float* H_R       = (const float*)d_in[6];
  const float* node_W    = (const float*)d_in[7];
  const float* node_b    = (const float*)d_in[8];
  const float* gcn_Wr    = (const float*)d_in[9];
  const float* gcn_Wroot = (const float*)d_in[10];
  const float* gcn_b     = (const float*)d_in[11];
  const float* pg_ls     = (const float*)d_in[12];
  const float* pu_W      = (const float*)d_in[13];
  const float* pu_b      = (const float*)d_in[14];
  const float* qz_W      = (const float*)d_in[15];
  const float* qz_b      = (const float*)d_in[16];
  const float* out_W1    = (const float*)d_in[17];
  const float* out_b1    = (const float*)d_in[18];
  const float* out_W2    = (const float*)d_in[19];
  const float* out_b2    = (const float*)d_in[20];
  float* out = (float*)d_out;

  char* base = (char*)d_ws;
  size_t off = 0;
  auto ALLOC = [&](size_t nbytes)->void*{
    void* p = base + off; off += (nbytes + 255) & ~(size_t)255; return p;
  };
  ushort* slabs   = (ushort*)ALLOC((size_t)5*N_NODESC*DC*2);     // [wroot, hrel0..3] bf16
  ushort* curb    = (ushort*)ALLOC((size_t)N_NODESC*DC*2);       // bf16 feats
  ushort* xb      = (ushort*)ALLOC((size_t)N_NODESC*D_INC*2);
  ushort* node_Wt = (ushort*)ALLOC((size_t)DC*D_INC*2);
  ushort* Wcat    = (ushort*)ALLOC((size_t)N_LAYERSC*1280*DC*2);
  // contiguous zero group: cnt | deg | cursor | scal
  float*  zgrp    = (float*) ALLOC((size_t)(N_RELC*N_NODESC + N_NODESC + N_NODESC + 16)*4);
  float*  cnt     = zgrp;
  int*    deg     = (int*)(cnt + (size_t)N_RELC*N_NODESC);
  int*    cursor  = deg + N_NODESC;
  float*  scal    = (float*)(cursor + N_NODESC);
  int*    rowptr  = (int*)   ALLOC((size_t)(N_NODESC+1)*4);
  int*    bsum    = (int*)   ALLOC((size_t)NBLK_SCAN*4);
  int*    boff    = (int*)   ALLOC((size_t)NBLK_SCAN*4);
  int*    ep      = (int*)   ALLOC((size_t)N_EDGESC*4);
  float*  einvc   = (float*) ALLOC((size_t)N_EDGESC*4);
  int*    grow    = (int*)   ALLOC((size_t)(NUM_MC+1)*4);
  float*  Hrelu   = (float*) ALLOC((size_t)1088*DC*4);
  float*  pu      = (float*) ALLOC((size_t)1088*512*4);
  float*  qz      = (float*) ALLOC((size_t)1088*512*4);
  float*  u       = (float*) ALLOC((size_t)1088*DC*4);
  float*  d2      = (float*) ALLOC((size_t)NUM_MC*NUM_RC*4);
  float*  An      = (float*) ALLOC((size_t)NUM_MC*NUM_RC*4);
  float*  pzcat   = (float*) ALLOC((size_t)NUM_MC*512*4);
  float*  repM    = (float*) ALLOC((size_t)NUM_MC*512*4);
  float*  repR    = (float*) ALLOC((size_t)NUM_RC*512*4);
  float*  hidM    = (float*) ALLOC((size_t)NUM_MC*256*4);
  float*  hidR    = (float*) ALLOC((size_t)NUM_RC*256*4);
  (void)ws_size; (void)in_sizes; (void)n_in; (void)out_size;

  uint32_t ya0,ya1,yb0,yb1,yc0,yc1,yd0,yd1;
  tf2x32(0u,42u, 0u,4u, &ya0,&ya1);
  tf2x32(0u,42u, 1u,5u, &yb0,&yb1);
  tf2x32(0u,42u, 2u,6u, &yc0,&yc1);
  tf2x32(0u,42u, 3u,7u, &yd0,&yd1);
  const uint32_t ku0=ya0,  ku1=yb0;
  const uint32_t ka0=yc0,  ka1=yd0;
  const uint32_t kzm0=ya1, kzm1=yb1;
  const uint32_t kzr0=yc1, kzr1=yd1;

  auto GEMM = [&](const float* A, int lda, const float* B, int ldb, float* C, int ldc,
                  int M, int N, int K, const float* bias, int flags){
    k_gemm<<<dim3(N/64, (M+63)/64), dim3(256), 0, stream>>>(A, lda, B, ldb, C, ldc, M, N, K, bias, flags);
  };
  auto BGEMM = [&](const ushort* A, int lda, const ushort* Bt, int ldb, void* C, int ldc,
                   int M, int N, int K, const float* bias, int flags, int gz,
                   size_t strideB, size_t strideC){
    k_gemm_bf16<<<dim3(N/128, (M+127)/128, gz), dim3(256), 0, stream>>>(
        A, lda, Bt, ldb, C, ldc, M, N, K, bias, flags, strideB, strideC);
  };

  // ---- setup: zero group, histograms, parallel scan, CSR, boundaries ----
  {
    int n4 = (N_RELC*N_NODESC + 2*N_NODESC + 16)/4;
    k_zero4<<<dim3((n4+255)/256), dim3(256), 0, stream>>>((float4*)zgrp, n4);
  }
  k_count<<<dim3((N_EDGESC+255)/256), dim3(256), 0, stream>>>(edge_index, edge_type, cnt, deg);
  k_scan1<<<dim3(NBLK_SCAN), dim3(256), 0, stream>>>(deg, bsum);
  k_scan2<<<dim3(1), dim3(256), 0, stream>>>(bsum, boff);
  k_scan3<<<dim3(NBLK_SCAN), dim3(256), 0, stream>>>(deg, boff, rowptr);
  k_fill2<<<dim3((N_EDGESC+255)/256), dim3(256), 0, stream>>>(edge_index, edge_type, cnt, rowptr, cursor, ep, einvc);
  k_bnd  <<<dim3((N_NODESC+255)/256), dim3(256), 0, stream>>>(batch, grow);

  // weight prep
  k_wt  <<<dim3((D_INC*DC+255)/256), dim3(256), 0, stream>>>(node_W, node_Wt, D_INC, DC, D_INC*DC);
  k_wcat<<<dim3((N_LAYERSC*1280*DC+255)/256), dim3(256), 0, stream>>>(gcn_Wroot, gcn_Wr, Wcat);
  {
    int n4 = (N_NODESC*D_INC)/4;
    k_cvt4<<<dim3((n4+255)/256), dim3(256), 0, stream>>>((const float4*)x, (ushort4*)xb, n4);
  }

  // ---- input projection: curb = bf16(x @ node_W + node_b) ----
  BGEMM(xb, D_INC, node_Wt, D_INC, curb, DC, N_NODESC, DC, D_INC, node_b, 1|2, 1, 0, 0);

  // ---- RGCN layers: one fused N=1280 GEMM -> 5 slabs; then CSR gather ----
  for (int l = 0; l < N_LAYERSC; l++){
    BGEMM(curb, DC, Wcat + (size_t)l*1280*DC, DC, slabs, DC, N_NODESC, 1280, DC,
          nullptr, 8, 1, 0, (size_t)N_NODESC*DC);
    k_gather<<<dim3((N_NODESC+3)/4), dim3(256), 0, stream>>>(
        slabs, gcn_b + l*DC, curb, (l < N_LAYERSC-1) ? 1 : 0, rowptr, ep, einvc);
  }
  // curb == final feats (bf16, no relu)

  // ---- pool + concat + relu ----
  k_pool<<<dim3((NUM_RC+NUM_MC+3)/4), dim3(256), 0, stream>>>(curb, grow, H_R, Hrelu);

  // ---- pu / qz projections (fp32) ----
  GEMM(Hrelu, DC, pu_W, 512, pu, 512, 1088, 512, DC, pu_b, 2);
  GEMM(Hrelu, DC, qz_W, 512, qz, 512, 1088, 512, DC, qz_b, 2);

  // ---- u sampling (also builds rep cols 256..511) ----
  k_sample_u<<<dim3(544), dim3(256), 0, stream>>>(pu, u, repR, repM, ku0, ku1);

  // ---- d2, A, An ----
  k_d2<<<dim3(NUM_MC), dim3(64), 0, stream>>>(u, d2);
  k_A <<<dim3(128), dim3(256), 0, stream>>>(d2, pg_ls, An, ka0, ka1);
  k_rownorm<<<dim3(NUM_MC), dim3(64), 0, stream>>>(An);

  // ---- pzcat = An @ qz[:64] (mean||ls in one GEMM) ----
  GEMM(An, NUM_RC, qz, 512, pzcat, 512, NUM_MC, 512, NUM_RC, nullptr, 0);

  // ---- z sampling + log_pqz ----
  k_sample_zM<<<dim3(512), dim3(256), 0, stream>>>(qz, repM, kzm0, kzm1);
  k_logpqz<<<dim3(1024), dim3(256), 0, stream>>>(repM, pzcat, qz, scal);
  k_sample_zR<<<dim3(32), dim3(256), 0, stream>>>(qz, repR, kzr0, kzr1);

  // ---- output heads (single K=512 GEMM each) ----
  GEMM(repM, 512, out_W1, 256, hidM, 256, NUM_MC, 256, 512, out_b1, 2|4);
  k_out_head<<<dim3(NUM_MC/4), dim3(256), 0, stream>>>(hidM, out_W2, out_b2, yM, scal+1, NUM_MC);

  GEMM(repR, 512, out_W1, 256, hidR, 256, NUM_RC, 256, 512, out_b1, 2|4);
  k_out_head<<<dim3(NUM_RC/4), dim3(256), 0, stream>>>(hidR, out_W2, out_b2, yR, scal+2, NUM_RC);

  // ---- reg term & final combine ----
  k_reg<<<dim3(128), dim3(256), 0, stream>>>(d2, yM, scal);
  k_final<<<dim3(1), dim3(1), 0, stream>>>(scal, out);
}